// Round 4
// baseline (416.738 us; speedup 1.0000x reference)
//
#include <hip/hip_runtime.h>
#include <hip/hip_cooperative_groups.h>

namespace cg = cooperative_groups;

#define N_NODES 50000
#define N_EDGES 800000
#define D 64
#define COARSE 196           // coarse bins of 256 nodes (tgt>>8)
#define CCAP 4480            // edges/coarse bin: mean 4096, sigma 64 -> +6 sigma
#define BINS 3125            // k2 bins of 16 nodes (= 50000/16 exactly)
#define BIN_NODES 16
#define NODE_CAP 64          // deg ~ Poisson(16); P(>64) ~ 1e-18
#define BROW 72              // u16 stride per node bucket in LDS (144 B)
#define KA_BLOCKS 391        // 2048 edges per vb (last: 1280)
#define KA_EDGES 2048
#define GEMV_BLOCKS 3125     // 16 rows per vb
#define CVT_BLOCKS 3125
#define K1_BLOCKS (KA_BLOCKS + GEMV_BLOCKS + CVT_BLOCKS)
#define SCAN_W 18            // ceil(CCAP/256) scan words per thread
#define GRID_MAX 1024

__device__ __forceinline__ unsigned int f2bf(float f) {
    unsigned int u = __builtin_bit_cast(unsigned int, f);
    return (u + 0x7fffu + ((u >> 16) & 1u)) >> 16;
}
__device__ __forceinline__ float bflo(unsigned int v) {
    return __builtin_bit_cast(float, v << 16);
}
__device__ __forceinline__ float bfhi(unsigned int v) {
    return __builtin_bit_cast(float, v & 0xffff0000u);
}

// ===========================================================================
// ROUND-16: cooperative fusion, COHERENCE-FIXED.
// R3 failure analysis: absmax 4.4375 == max|lap| -> the lap term vanished.
// Cause: phase-0 zeroed gCur with PLAIN STORES (dirty in one XCD's L2) while
// KA's atomicAdd RMWs execute at the device coherence point past L2 -> the
// atomics accumulated onto workspace poison, and the late writeback of the
// zero-lines could clobber the sums. Fix: install the zeros with atomicExch
// (same coherence point as the adds) and read cnt back with atomicAdd(p,0).
// Bulk paths (gPairs/data16/out) keep plain stores fenced by
// __threadfence()+grid.sync() (release/acquire at agent scope).
// Launch robustness: grid sized from the occupancy API; stride = gridDim.x;
// if hipLaunchCooperativeKernel declines, fall back to the proven R2
// 3-launch path (same phase bodies).
// ===========================================================================
__global__ __launch_bounds__(256, 4) void fused_kernel(
        const float* __restrict__ data,
        const float* __restrict__ merge,
        const int* __restrict__ src, const int* __restrict__ tgt,
        const float* __restrict__ W_lin,
        const float* __restrict__ W_tr, const float* __restrict__ b_tr,
        unsigned short* __restrict__ data16,
        int* __restrict__ gCur, unsigned int* __restrict__ gPairs,
        float* __restrict__ out) {
    __shared__ __align__(16) unsigned int epair[KA_EDGES];   // 8 KB
    __shared__ int hist[COARSE], rbase[COARSE], cur2[COARSE];
    __shared__ __align__(16) unsigned short lbkt[BIN_NODES * BROW];  // 2.25 KB
    __shared__ int lcur[BIN_NODES];
    __shared__ float hbuf[BIN_NODES * D];                            // 4 KB

    cg::grid_group grid = cg::this_grid();
    int tid = threadIdx.x;
    int p = blockIdx.x;
    int gstride = gridDim.x;

    // ---- phase 0: zero gCur AT THE COHERENCE POINT (atomicExch, not plain
    // store -- plain stores sit dirty in one XCD's L2 while the KA atomics
    // RMW at the device-scope point past L2). --------------------------------
    if (p == 0) atomicExch(&gCur[tid], 0);       // 256 ints (COARSE=196 used)
    grid.sync();

    // ======================= phase B: k1 roles =============================
    for (int b = p; b < K1_BLOCKS; b += gstride) {
        if (b < KA_BLOCKS) {
            int eb = b * KA_EDGES;
            int n = N_EDGES - eb; if (n > KA_EDGES) n = KA_EDGES;
            if (tid < COARSE) { hist[tid] = 0; cur2[tid] = 0; }
            __syncthreads();
            for (int i = tid; i < n; i += 256) {
                int t = tgt[eb + i];
                unsigned int pr = ((unsigned int)t << 16) | (unsigned int)src[eb + i];
                epair[i] = pr;
                atomicAdd(&hist[t >> 8], 1);
            }
            __syncthreads();
            if (tid < COARSE && hist[tid] > 0)
                rbase[tid] = atomicAdd(&gCur[tid], hist[tid]);
            __syncthreads();
            for (int i = tid; i < n; i += 256) {
                unsigned int pr = epair[i];
                int c = pr >> 24;                        // tgt>>8
                int pos = rbase[c] + atomicAdd(&cur2[c], 1);
                if (pos < CCAP) gPairs[(size_t)c * CCAP + pos] = pr;
            }
        } else if (b < KA_BLOCKS + GEMV_BLOCKS) {
            int gb = b - KA_BLOCKS;
            int lane = tid & 63;
            float* mtile = (float*)epair;               // 4 KB alias
            float4 Wr[16];
            const float4* wrow = (const float4*)(W_tr + (size_t)lane * D);
#pragma unroll
            for (int i = 0; i < 16; i++) Wr[i] = wrow[i];
            float bias = b_tr[lane];
            ((float4*)mtile)[tid] =
                ((const float4*)(merge + (size_t)gb * 16 * D))[tid];
            __syncthreads();
            int w = tid >> 6;
#pragma unroll
            for (int tg = 0; tg < 4; tg++) {
                int t = w * 4 + tg;
                const float4* hrow = (const float4*)(mtile + t * D);
                float acc = bias;
#pragma unroll
                for (int i = 0; i < 16; i++) {
                    float4 hq = hrow[i];            // broadcast read
                    acc += hq.x * Wr[i].x + hq.y * Wr[i].y
                         + hq.z * Wr[i].z + hq.w * Wr[i].w;
                }
                out[(size_t)(gb * 16 + t) * D + lane] = acc;
            }
        } else {
            int i = (b - KA_BLOCKS - GEMV_BLOCKS) * 256 + tid;   // float4 index
            float4 d = ((const float4*)data)[i];
            uint2 v;
            v.x = f2bf(d.x) | (f2bf(d.y) << 16);
            v.y = f2bf(d.z) | (f2bf(d.w) << 16);
            ((uint2*)data16)[i] = v;
        }
        __syncthreads();    // LDS (epair/mtile) reuse across vb iterations
    }

    __threadfence();        // release: gPairs/data16/out stores -> visible
    grid.sync();

    // ======================= phase C: k2 bins ==============================
    for (int bin = p; bin < BINS; bin += gstride) {
        int lane = tid & 63;
        int c = bin >> 4;                    // parent coarse bin
        int s = bin & 15;                    // 16-node sub-bin within it
        int nodeBase = bin * BIN_NODES;

        int G = tid >> 3;
        int ln = tid & 7;
        int node = G >> 1;
        int par = G & 1;
        int n = nodeBase + node;

        if (tid < BIN_NODES) lcur[tid] = 0;
        __syncthreads();

        // cnt: atomic read at the same coherence point the adds used
        int cnt;
        if (tid == 0) { cnt = atomicAdd(&gCur[c], 0); }
        cnt = __shfl(cnt, 0);                       // wave 0 lane 0 -> wave
        __shared__ int cnt_sh;
        if (tid == 0) cnt_sh = cnt;
        __syncthreads();
        cnt = cnt_sh;
        if (cnt > CCAP) cnt = CCAP;

        // ---- scan phase A: issue all loads unconditionally (clamped) ------
        const unsigned int* cp = gPairs + (size_t)c * CCAP;
        unsigned int pw[SCAN_W];
#pragma unroll
        for (int j = 0; j < SCAN_W; j++) {
            int i = j * 256 + tid;
            pw[j] = cp[i < cnt ? i : 0];
        }
        const float4* orow = (const float4*)(data + (size_t)n * D + 8 * ln);
        float4 o0 = orow[0], o1 = orow[1];

        // ---- scan phase B: register-only processing + LDS appends ---------
#pragma unroll
        for (int j = 0; j < SCAN_W; j++) {
            int i = j * 256 + tid;
            unsigned int pr = pw[j];
            int tl = (pr >> 16) & 255;
            if (i < cnt && (tl >> 4) == s) {
                int nd = tl & 15;
                int pos = atomicAdd(&lcur[nd], 1);
                if (pos < NODE_CAP)
                    lbkt[nd * BROW + pos] = (unsigned short)(pr & 0xffffu);
            }
        }
        __syncthreads();

        // ---- gather ------------------------------------------------------
        int dg = lcur[node];
        int dgc = dg < NODE_CAP ? dg : NODE_CAP;

        const uint2* idxp = (const uint2*)(lbkt + node * BROW + par * 4);
        uint2 iw0 = idxp[0], iw1 = idxp[2], iw2 = idxp[4], iw3 = idxp[6];

        float af[4][8];
#pragma unroll
        for (int ch = 0; ch < 4; ch++)
#pragma unroll
            for (int k = 0; k < 8; k++) af[ch][k] = 0.f;

        {   // fast window: edges 0..15 -- branchless
            unsigned int idx[8]; float m[8];
            unsigned int iww[4] = { iw0.x, iw0.y, iw1.x, iw1.y };
#pragma unroll
            for (int q = 0; q < 4; q++) {
                int e = (q >> 1) * 8 + par * 4 + (q & 1) * 2;
                unsigned int lo = iww[q] & 0xffffu, hi = iww[q] >> 16;
                idx[q * 2]     = e     < dgc ? lo : 0u;
                m[q * 2]       = e     < dgc ? 1.f : 0.f;
                idx[q * 2 + 1] = e + 1 < dgc ? hi : 0u;
                m[q * 2 + 1]   = e + 1 < dgc ? 1.f : 0.f;
            }
            uint4 v[8];
#pragma unroll
            for (int k = 0; k < 8; k++)
                v[k] = *(const uint4*)(data16 + (size_t)idx[k] * D + 8 * ln);
#pragma unroll
            for (int k = 0; k < 8; k++) {
                int ch = k & 3;
                af[ch][0] += m[k] * bflo(v[k].x); af[ch][1] += m[k] * bfhi(v[k].x);
                af[ch][2] += m[k] * bflo(v[k].y); af[ch][3] += m[k] * bfhi(v[k].y);
                af[ch][4] += m[k] * bflo(v[k].z); af[ch][5] += m[k] * bfhi(v[k].z);
                af[ch][6] += m[k] * bflo(v[k].w); af[ch][7] += m[k] * bfhi(v[k].w);
            }
        }
#pragma unroll
        for (int it = 2; it < 4; it++) {
            int e0 = it * 8 + par * 4;
            if (e0 < dgc) {
                uint2 iw = (it == 2) ? iw2 : iw3;
                unsigned int i0 = iw.x & 0xffffu, i1 = iw.x >> 16;
                unsigned int i2 = iw.y & 0xffffu, i3 = iw.y >> 16;
                unsigned int jdx[4]; float mm[4];
                jdx[0] = i0;                       mm[0] = 1.f;
                jdx[1] = e0 + 1 < dgc ? i1 : 0u;   mm[1] = e0 + 1 < dgc ? 1.f : 0.f;
                jdx[2] = e0 + 2 < dgc ? i2 : 0u;   mm[2] = e0 + 2 < dgc ? 1.f : 0.f;
                jdx[3] = e0 + 3 < dgc ? i3 : 0u;   mm[3] = e0 + 3 < dgc ? 1.f : 0.f;
                uint4 vv[4];
#pragma unroll
                for (int k = 0; k < 4; k++)
                    vv[k] = *(const uint4*)(data16 + (size_t)jdx[k] * D + 8 * ln);
#pragma unroll
                for (int k = 0; k < 4; k++) {
                    af[k][0] += mm[k] * bflo(vv[k].x); af[k][1] += mm[k] * bfhi(vv[k].x);
                    af[k][2] += mm[k] * bflo(vv[k].y); af[k][3] += mm[k] * bfhi(vv[k].y);
                    af[k][4] += mm[k] * bflo(vv[k].z); af[k][5] += mm[k] * bfhi(vv[k].z);
                    af[k][6] += mm[k] * bflo(vv[k].w); af[k][7] += mm[k] * bfhi(vv[k].w);
                }
            }
        }
        int nIt = (dgc + 7) >> 3;
        for (int it = 4; it < nIt; it++) {
            uint2 iw = idxp[it * 2];
            int e0 = it * 8 + par * 4;
            unsigned int i0 = iw.x & 0xffffu, i1 = iw.x >> 16;
            unsigned int i2 = iw.y & 0xffffu, i3 = iw.y >> 16;
            unsigned int jdx[4]; float mm[4];
            jdx[0] = e0     < dgc ? i0 : 0u;   mm[0] = e0     < dgc ? 1.f : 0.f;
            jdx[1] = e0 + 1 < dgc ? i1 : 0u;   mm[1] = e0 + 1 < dgc ? 1.f : 0.f;
            jdx[2] = e0 + 2 < dgc ? i2 : 0u;   mm[2] = e0 + 2 < dgc ? 1.f : 0.f;
            jdx[3] = e0 + 3 < dgc ? i3 : 0u;   mm[3] = e0 + 3 < dgc ? 1.f : 0.f;
            uint4 vv[4];
#pragma unroll
            for (int k = 0; k < 4; k++)
                vv[k] = *(const uint4*)(data16 + (size_t)jdx[k] * D + 8 * ln);
#pragma unroll
            for (int k = 0; k < 4; k++) {
                af[k][0] += mm[k] * bflo(vv[k].x); af[k][1] += mm[k] * bfhi(vv[k].x);
                af[k][2] += mm[k] * bflo(vv[k].y); af[k][3] += mm[k] * bfhi(vv[k].y);
                af[k][4] += mm[k] * bflo(vv[k].z); af[k][5] += mm[k] * bfhi(vv[k].z);
                af[k][6] += mm[k] * bflo(vv[k].w); af[k][7] += mm[k] * bfhi(vv[k].w);
            }
        }

        float sv[8];
#pragma unroll
        for (int k = 0; k < 8; k++)
            sv[k] = (af[0][k] + af[1][k]) + (af[2][k] + af[3][k]);
#pragma unroll
        for (int k = 0; k < 8; k++) sv[k] += __shfl_xor(sv[k], 8);

        if (par == 0) {
            float inv = dg > 0 ? 1.0f / (float)dg : 0.0f;
            float msk = dg > 0 ? 1.0f : 0.0f;
            float4 h0, h1;
            h0.x = (o0.x - sv[0] * inv) * msk; h0.y = (o0.y - sv[1] * inv) * msk;
            h0.z = (o0.z - sv[2] * inv) * msk; h0.w = (o0.w - sv[3] * inv) * msk;
            h1.x = (o1.x - sv[4] * inv) * msk; h1.y = (o1.y - sv[5] * inv) * msk;
            h1.z = (o1.z - sv[6] * inv) * msk; h1.w = (o1.w - sv[7] * inv) * msk;
            float4* hp = (float4*)(hbuf + node * D + 8 * ln);
            hp[0] = h0; hp[1] = h1;
        }

        // ---- GEMV operand prefetch hidden under the barrier ---------------
        float4 Wr[16];
        const float4* wrow = (const float4*)(W_lin + (size_t)lane * D);
#pragma unroll
        for (int i = 0; i < 16; i++) Wr[i] = wrow[i];
        int w = tid >> 6;
        float oldv[4];
#pragma unroll
        for (int tg = 0; tg < 4; tg++)
            oldv[tg] = out[(size_t)(nodeBase + w * 4 + tg) * D + lane];
        __syncthreads();

#pragma unroll
        for (int tg = 0; tg < 4; tg++) {
            int t = w * 4 + tg;
            int nn = nodeBase + t;
            const float4* hrow = (const float4*)(hbuf + t * D);
            float acc = 0.f;
#pragma unroll
            for (int i = 0; i < 16; i++) {
                float4 hq = hrow[i];
                acc += hq.x * Wr[i].x + hq.y * Wr[i].y
                     + hq.z * Wr[i].z + hq.w * Wr[i].w;
            }
            float o = acc + oldv[tg];
            out[(size_t)nn * D + lane] = o > 0.f ? o : 0.f;
        }
        __syncthreads();    // LDS reuse across bin iterations
    }
}

// ===========================================================================
// Fallback path: R2's proven 3-launch structure (byte-identical bodies).
// ===========================================================================
__global__ __launch_bounds__(256) void k1_kernel(
        const float* __restrict__ data,
        const float* __restrict__ merge,
        const int* __restrict__ src, const int* __restrict__ tgt,
        const float* __restrict__ W_tr, const float* __restrict__ b_tr,
        unsigned short* __restrict__ data16,
        int* __restrict__ gCur, unsigned int* __restrict__ gPairs,
        float* __restrict__ outv) {
    __shared__ __align__(16) unsigned int epair[KA_EDGES];
    __shared__ int hist[COARSE], rbase[COARSE], cur2[COARSE];
    int b = blockIdx.x;
    int tid = threadIdx.x;
    if (b < KA_BLOCKS) {
        int eb = b * KA_EDGES;
        int n = N_EDGES - eb; if (n > KA_EDGES) n = KA_EDGES;
        if (tid < COARSE) { hist[tid] = 0; cur2[tid] = 0; }
        __syncthreads();
        for (int i = tid; i < n; i += 256) {
            int t = tgt[eb + i];
            unsigned int p = ((unsigned int)t << 16) | (unsigned int)src[eb + i];
            epair[i] = p;
            atomicAdd(&hist[t >> 8], 1);
        }
        __syncthreads();
        if (tid < COARSE && hist[tid] > 0)
            rbase[tid] = atomicAdd(&gCur[tid], hist[tid]);
        __syncthreads();
        for (int i = tid; i < n; i += 256) {
            unsigned int p = epair[i];
            int c = p >> 24;
            int pos = rbase[c] + atomicAdd(&cur2[c], 1);
            if (pos < CCAP) gPairs[(size_t)c * CCAP + pos] = p;
        }
    } else if (b < KA_BLOCKS + GEMV_BLOCKS) {
        int gb = b - KA_BLOCKS;
        int lane = tid & 63;
        float* mtile = (float*)epair;
        float4 Wr[16];
        const float4* wrow = (const float4*)(W_tr + (size_t)lane * D);
#pragma unroll
        for (int i = 0; i < 16; i++) Wr[i] = wrow[i];
        float bias = b_tr[lane];
        ((float4*)mtile)[tid] =
            ((const float4*)(merge + (size_t)gb * 16 * D))[tid];
        __syncthreads();
        int w = tid >> 6;
#pragma unroll
        for (int tg = 0; tg < 4; tg++) {
            int t = w * 4 + tg;
            const float4* hrow = (const float4*)(mtile + t * D);
            float acc = bias;
#pragma unroll
            for (int i = 0; i < 16; i++) {
                float4 hq = hrow[i];
                acc += hq.x * Wr[i].x + hq.y * Wr[i].y
                     + hq.z * Wr[i].z + hq.w * Wr[i].w;
            }
            outv[(size_t)(gb * 16 + t) * D + lane] = acc;
        }
    } else {
        int i = (b - KA_BLOCKS - GEMV_BLOCKS) * 256 + tid;
        float4 d = ((const float4*)data)[i];
        uint2 v;
        v.x = f2bf(d.x) | (f2bf(d.y) << 16);
        v.y = f2bf(d.z) | (f2bf(d.w) << 16);
        ((uint2*)data16)[i] = v;
    }
}

__global__ __launch_bounds__(256) void k2_kernel(
        const float* __restrict__ data,
        const unsigned short* __restrict__ data16,
        const int* __restrict__ gCur,
        const unsigned int* __restrict__ gPairs,
        const float* __restrict__ W_lin,
        float* __restrict__ out) {
    __shared__ __align__(16) unsigned short lbkt[BIN_NODES * BROW];
    __shared__ int lcur[BIN_NODES];
    __shared__ float hbuf[BIN_NODES * D];

    int tid = threadIdx.x;
    int lane = tid & 63;
    int bin = blockIdx.x;
    int c = bin >> 4;
    int s = bin & 15;
    int nodeBase = bin * BIN_NODES;

    int G = tid >> 3;
    int ln = tid & 7;
    int node = G >> 1;
    int par = G & 1;
    int n = nodeBase + node;

    if (tid < BIN_NODES) lcur[tid] = 0;
    __syncthreads();

    int cnt = gCur[c]; if (cnt > CCAP) cnt = CCAP;
    const unsigned int* cp = gPairs + (size_t)c * CCAP;
    unsigned int pw[SCAN_W];
#pragma unroll
    for (int j = 0; j < SCAN_W; j++) {
        int i = j * 256 + tid;
        pw[j] = cp[i < cnt ? i : 0];
    }
    const float4* orow = (const float4*)(data + (size_t)n * D + 8 * ln);
    float4 o0 = orow[0], o1 = orow[1];

#pragma unroll
    for (int j = 0; j < SCAN_W; j++) {
        int i = j * 256 + tid;
        unsigned int p = pw[j];
        int tl = (p >> 16) & 255;
        if (i < cnt && (tl >> 4) == s) {
            int nd = tl & 15;
            int pos = atomicAdd(&lcur[nd], 1);
            if (pos < NODE_CAP)
                lbkt[nd * BROW + pos] = (unsigned short)(p & 0xffffu);
        }
    }
    __syncthreads();

    int dg = lcur[node];
    int dgc = dg < NODE_CAP ? dg : NODE_CAP;

    const uint2* idxp = (const uint2*)(lbkt + node * BROW + par * 4);
    uint2 iw0 = idxp[0], iw1 = idxp[2], iw2 = idxp[4], iw3 = idxp[6];

    float af[4][8];
#pragma unroll
    for (int ch = 0; ch < 4; ch++)
#pragma unroll
        for (int k = 0; k < 8; k++) af[ch][k] = 0.f;

    {
        unsigned int idx[8]; float m[8];
        unsigned int iww[4] = { iw0.x, iw0.y, iw1.x, iw1.y };
#pragma unroll
        for (int q = 0; q < 4; q++) {
            int e = (q >> 1) * 8 + par * 4 + (q & 1) * 2;
            unsigned int lo = iww[q] & 0xffffu, hi = iww[q] >> 16;
            idx[q * 2]     = e     < dgc ? lo : 0u;
            m[q * 2]       = e     < dgc ? 1.f : 0.f;
            idx[q * 2 + 1] = e + 1 < dgc ? hi : 0u;
            m[q * 2 + 1]   = e + 1 < dgc ? 1.f : 0.f;
        }
        uint4 v[8];
#pragma unroll
        for (int k = 0; k < 8; k++)
            v[k] = *(const uint4*)(data16 + (size_t)idx[k] * D + 8 * ln);
#pragma unroll
        for (int k = 0; k < 8; k++) {
            int ch = k & 3;
            af[ch][0] += m[k] * bflo(v[k].x); af[ch][1] += m[k] * bfhi(v[k].x);
            af[ch][2] += m[k] * bflo(v[k].y); af[ch][3] += m[k] * bfhi(v[k].y);
            af[ch][4] += m[k] * bflo(v[k].z); af[ch][5] += m[k] * bfhi(v[k].z);
            af[ch][6] += m[k] * bflo(v[k].w); af[ch][7] += m[k] * bfhi(v[k].w);
        }
    }
#pragma unroll
    for (int it = 2; it < 4; it++) {
        int e0 = it * 8 + par * 4;
        if (e0 < dgc) {
            uint2 iw = (it == 2) ? iw2 : iw3;
            unsigned int i0 = iw.x & 0xffffu, i1 = iw.x >> 16;
            unsigned int i2 = iw.y & 0xffffu, i3 = iw.y >> 16;
            unsigned int jdx[4]; float mm[4];
            jdx[0] = i0;                       mm[0] = 1.f;
            jdx[1] = e0 + 1 < dgc ? i1 : 0u;   mm[1] = e0 + 1 < dgc ? 1.f : 0.f;
            jdx[2] = e0 + 2 < dgc ? i2 : 0u;   mm[2] = e0 + 2 < dgc ? 1.f : 0.f;
            jdx[3] = e0 + 3 < dgc ? i3 : 0u;   mm[3] = e0 + 3 < dgc ? 1.f : 0.f;
            uint4 vv[4];
#pragma unroll
            for (int k = 0; k < 4; k++)
                vv[k] = *(const uint4*)(data16 + (size_t)jdx[k] * D + 8 * ln);
#pragma unroll
            for (int k = 0; k < 4; k++) {
                af[k][0] += mm[k] * bflo(vv[k].x); af[k][1] += mm[k] * bfhi(vv[k].x);
                af[k][2] += mm[k] * bflo(vv[k].y); af[k][3] += mm[k] * bfhi(vv[k].y);
                af[k][4] += mm[k] * bflo(vv[k].z); af[k][5] += mm[k] * bfhi(vv[k].z);
                af[k][6] += mm[k] * bflo(vv[k].w); af[k][7] += mm[k] * bfhi(vv[k].w);
            }
        }
    }
    int nIt = (dgc + 7) >> 3;
    for (int it = 4; it < nIt; it++) {
        uint2 iw = idxp[it * 2];
        int e0 = it * 8 + par * 4;
        unsigned int i0 = iw.x & 0xffffu, i1 = iw.x >> 16;
        unsigned int i2 = iw.y & 0xffffu, i3 = iw.y >> 16;
        unsigned int jdx[4]; float mm[4];
        jdx[0] = e0     < dgc ? i0 : 0u;   mm[0] = e0     < dgc ? 1.f : 0.f;
        jdx[1] = e0 + 1 < dgc ? i1 : 0u;   mm[1] = e0 + 1 < dgc ? 1.f : 0.f;
        jdx[2] = e0 + 2 < dgc ? i2 : 0u;   mm[2] = e0 + 2 < dgc ? 1.f : 0.f;
        jdx[3] = e0 + 3 < dgc ? i3 : 0u;   mm[3] = e0 + 3 < dgc ? 1.f : 0.f;
        uint4 vv[4];
#pragma unroll
        for (int k = 0; k < 4; k++)
            vv[k] = *(const uint4*)(data16 + (size_t)jdx[k] * D + 8 * ln);
#pragma unroll
        for (int k = 0; k < 4; k++) {
            af[k][0] += mm[k] * bflo(vv[k].x); af[k][1] += mm[k] * bfhi(vv[k].x);
            af[k][2] += mm[k] * bflo(vv[k].y); af[k][3] += mm[k] * bfhi(vv[k].y);
            af[k][4] += mm[k] * bflo(vv[k].z); af[k][5] += mm[k] * bfhi(vv[k].z);
            af[k][6] += mm[k] * bflo(vv[k].w); af[k][7] += mm[k] * bfhi(vv[k].w);
        }
    }

    float sv[8];
#pragma unroll
    for (int k = 0; k < 8; k++)
        sv[k] = (af[0][k] + af[1][k]) + (af[2][k] + af[3][k]);
#pragma unroll
    for (int k = 0; k < 8; k++) sv[k] += __shfl_xor(sv[k], 8);

    if (par == 0) {
        float inv = dg > 0 ? 1.0f / (float)dg : 0.0f;
        float msk = dg > 0 ? 1.0f : 0.0f;
        float4 h0, h1;
        h0.x = (o0.x - sv[0] * inv) * msk; h0.y = (o0.y - sv[1] * inv) * msk;
        h0.z = (o0.z - sv[2] * inv) * msk; h0.w = (o0.w - sv[3] * inv) * msk;
        h1.x = (o1.x - sv[4] * inv) * msk; h1.y = (o1.y - sv[5] * inv) * msk;
        h1.z = (o1.z - sv[6] * inv) * msk; h1.w = (o1.w - sv[7] * inv) * msk;
        float4* hp = (float4*)(hbuf + node * D + 8 * ln);
        hp[0] = h0; hp[1] = h1;
    }

    float4 Wr[16];
    const float4* wrow = (const float4*)(W_lin + (size_t)lane * D);
#pragma unroll
    for (int i = 0; i < 16; i++) Wr[i] = wrow[i];
    int w = tid >> 6;
    float oldv[4];
#pragma unroll
    for (int tg = 0; tg < 4; tg++)
        oldv[tg] = out[(size_t)(nodeBase + w * 4 + tg) * D + lane];
    __syncthreads();

#pragma unroll
    for (int tg = 0; tg < 4; tg++) {
        int t = w * 4 + tg;
        int nn = nodeBase + t;
        const float4* hrow = (const float4*)(hbuf + t * D);
        float acc = 0.f;
#pragma unroll
        for (int i = 0; i < 16; i++) {
            float4 hq = hrow[i];
            acc += hq.x * Wr[i].x + hq.y * Wr[i].y
                 + hq.z * Wr[i].z + hq.w * Wr[i].w;
        }
        float o = acc + oldv[tg];
        out[(size_t)nn * D + lane] = o > 0.f ? o : 0.f;
    }
}

extern "C" void kernel_launch(void* const* d_in, const int* in_sizes, int n_in,
                              void* d_out, int out_size, void* d_ws, size_t ws_size,
                              hipStream_t stream) {
    const float* data  = (const float*)d_in[0];
    const float* merge = (const float*)d_in[1];
    const int*   src   = (const int*)d_in[2];
    const int*   tgt   = (const int*)d_in[3];
    const float* W_lin = (const float*)d_in[4];
    const float* W_tr  = (const float*)d_in[6];
    const float* b_tr  = (const float*)d_in[7];
    float* out = (float*)d_out;

    char* ws = (char*)d_ws;
    size_t o = 0;
    int*            gCur   = (int*)(ws + o);            o += 256 * 4;
    unsigned int*   gPairs = (unsigned int*)(ws + o);   o += (size_t)COARSE * CCAP * 4;
    unsigned short* data16 = (unsigned short*)(ws + o); o += (size_t)N_NODES * D * 2;

    // co-residency bound from the occupancy API (host-only, capture-safe)
    static int grid_cached = -1;
    if (grid_cached < 0) {
        int maxb = 0;
        hipError_t oe = hipOccupancyMaxActiveBlocksPerMultiprocessor(
            &maxb, fused_kernel, 256, 0);
        grid_cached = (oe == hipSuccess && maxb > 0)
                      ? (maxb * 256 < GRID_MAX ? maxb * 256 : GRID_MAX) : 0;
    }

    bool launched = false;
    if (grid_cached > 0) {
        void* args[] = {
            (void*)&data, (void*)&merge, (void*)&src, (void*)&tgt,
            (void*)&W_lin, (void*)&W_tr, (void*)&b_tr,
            (void*)&data16, (void*)&gCur, (void*)&gPairs, (void*)&out
        };
        hipError_t e = hipLaunchCooperativeKernel(
            (void*)fused_kernel, dim3(grid_cached), dim3(256), args, 0, stream);
        launched = (e == hipSuccess);
    }

    if (!launched) {
        // proven R2 path
        hipMemsetAsync(gCur, 0, 256 * 4, stream);
        k1_kernel<<<K1_BLOCKS, 256, 0, stream>>>(
            data, merge, src, tgt, W_tr, b_tr, data16, gCur, gPairs, out);
        k2_kernel<<<BINS, 256, 0, stream>>>(
            data, data16, gCur, gPairs, W_lin, out);
    }
}

// Round 5
// 174.562 us; speedup vs baseline: 2.3873x; 2.3873x over previous
//
#include <hip/hip_runtime.h>

#define N_NODES 50000
#define N_EDGES 800000
#define D 64
#define COARSE 196           // coarse bins of 256 nodes (tgt>>8)
#define CCAP 4480            // edges/coarse bin: mean 4096, sigma 64 -> +6 sigma
#define BINS 3125            // k2 bins of 16 nodes (= 50000/16 exactly)
#define BIN_NODES 16
#define NODE_CAP 64          // deg ~ Poisson(16); P(>64) ~ 1e-18
#define BROW 72              // u16 stride per node bucket in LDS (144 B)
#define KA_BLOCKS 391        // 2048 edges per block (last: 1280)
#define KA_EDGES 2048
#define CVT_BLOCKS 3125
#define K1_BLOCKS (KA_BLOCKS + CVT_BLOCKS)
#define SCAN_W 18            // ceil(CCAP/256) scan words per thread

__device__ __forceinline__ unsigned int f2bf(float f) {
    unsigned int u = __builtin_bit_cast(unsigned int, f);
    return (u + 0x7fffu + ((u >> 16) & 1u)) >> 16;
}
__device__ __forceinline__ float bflo(unsigned int v) {
    return __builtin_bit_cast(float, v << 16);
}
__device__ __forceinline__ float bfhi(unsigned int v) {
    return __builtin_bit_cast(float, v & 0xffff0000u);
}

// ---------------------------------------------------------------------------
// ROUND-17: back to the PROVEN 3-launch structure (R4's cooperative fusion
// inflated HBM traffic 6x -- FETCH 74->273 MB -- coop launch broke L2
// absorption of the redundant scan / W-fragment / scatter traffic; dead end).
// Change vs R2: the merge@W_tr^T+b_tr GEMV moves from k1 into k2's epilogue.
//  - out becomes write-once: -12.8 MB read, -12.8 MB write system-wide.
//  - k1 = KA binning (391 blocks, long pole, all start t=0) + CVT backfill.
//  - k2 runs two GEMV passes sharing ONE 64-VGPR weight fragment register
//    set (W_tr pass first, then reload with W_lin) to cap VGPR pressure.
// ---------------------------------------------------------------------------
__global__ __launch_bounds__(256) void k1_kernel(
        const float* __restrict__ data,
        const int* __restrict__ src, const int* __restrict__ tgt,
        unsigned short* __restrict__ data16,
        int* __restrict__ gCur, unsigned int* __restrict__ gPairs) {
    __shared__ __align__(16) unsigned int epair[KA_EDGES];   // 8 KB
    __shared__ int hist[COARSE], rbase[COARSE], cur2[COARSE];
    int b = blockIdx.x;
    int tid = threadIdx.x;
    if (b < KA_BLOCKS) {
        int eb = b * KA_EDGES;
        int n = N_EDGES - eb; if (n > KA_EDGES) n = KA_EDGES;
        if (tid < COARSE) { hist[tid] = 0; cur2[tid] = 0; }
        __syncthreads();
        for (int i = tid; i < n; i += 256) {
            int t = tgt[eb + i];
            unsigned int p = ((unsigned int)t << 16) | (unsigned int)src[eb + i];
            epair[i] = p;
            atomicAdd(&hist[t >> 8], 1);
        }
        __syncthreads();
        if (tid < COARSE && hist[tid] > 0)
            rbase[tid] = atomicAdd(&gCur[tid], hist[tid]);
        __syncthreads();
        for (int i = tid; i < n; i += 256) {
            unsigned int p = epair[i];
            int c = p >> 24;                        // tgt>>8
            int pos = rbase[c] + atomicAdd(&cur2[c], 1);
            if (pos < CCAP) gPairs[(size_t)c * CCAP + pos] = p;
        }
    } else {
        int i = (b - KA_BLOCKS) * 256 + tid;        // float4 index
        float4 d = ((const float4*)data)[i];
        uint2 v;
        v.x = f2bf(d.x) | (f2bf(d.y) << 16);
        v.y = f2bf(d.z) | (f2bf(d.w) << 16);
        ((uint2*)data16)[i] = v;
    }
}

// ---------------------------------------------------------------------------
// K2: one block per 16-node bin.
//  1. scan parent coarse bin (R2's two-phase: 18 unconditional clamped loads,
//     then register-only LDS-append pass) -> per-node buckets in LDS.
//  2. merge tile (16 rows, 4 KB) staged to LDS behind the scan loads.
//  3. gather: branchless fast window (edges 0..15), coarse-guarded 16..31,
//     dynamic tail >32. h rows -> hbuf.
//  4. epilogue: acc = b_tr + m@W_tr^T (pass 1), then reload fragment and
//     acc += h@W_lin^T (pass 2), relu, single out write.
// ---------------------------------------------------------------------------
__global__ __launch_bounds__(256) void k2_kernel(
        const float* __restrict__ data,
        const float* __restrict__ merge,
        const unsigned short* __restrict__ data16,
        const int* __restrict__ gCur,
        const unsigned int* __restrict__ gPairs,
        const float* __restrict__ W_lin,
        const float* __restrict__ W_tr, const float* __restrict__ b_tr,
        float* __restrict__ out) {
    __shared__ __align__(16) unsigned short lbkt[BIN_NODES * BROW];  // 2.25 KB
    __shared__ int lcur[BIN_NODES];
    __shared__ float hbuf[BIN_NODES * D];                            // 4 KB
    __shared__ float mbuf[BIN_NODES * D];                            // 4 KB

    int tid = threadIdx.x;
    int lane = tid & 63;
    int bin = blockIdx.x;
    int c = bin >> 4;                    // parent coarse bin
    int s = bin & 15;                    // 16-node sub-bin within it
    int nodeBase = bin * BIN_NODES;

    // gather geometry (needed early for the data-row prefetch)
    int G = tid >> 3;
    int ln = tid & 7;
    int node = G >> 1;
    int par = G & 1;
    int n = nodeBase + node;

    if (tid < BIN_NODES) lcur[tid] = 0;
    __syncthreads();

    // ---- scan phase A: issue all loads unconditionally (clamped) ----------
    int cnt = gCur[c]; if (cnt > CCAP) cnt = CCAP;
    const unsigned int* cp = gPairs + (size_t)c * CCAP;
    unsigned int pw[SCAN_W];
#pragma unroll
    for (int j = 0; j < SCAN_W; j++) {
        int i = j * 256 + tid;
        pw[j] = cp[i < cnt ? i : 0];
    }
    // merge tile + own data row ride behind the scan loads (latency hidden)
    float4 mrow_ld = ((const float4*)(merge + (size_t)nodeBase * D))[tid];
    const float4* orow = (const float4*)(data + (size_t)n * D + 8 * ln);
    float4 o0 = orow[0], o1 = orow[1];
    float bias = b_tr[lane];

    // ---- scan phase B: register-only processing + LDS appends -------------
#pragma unroll
    for (int j = 0; j < SCAN_W; j++) {
        int i = j * 256 + tid;
        unsigned int pr = pw[j];
        int tl = (pr >> 16) & 255;       // local node within coarse bin
        if (i < cnt && (tl >> 4) == s) {
            int nd = tl & 15;
            int pos = atomicAdd(&lcur[nd], 1);
            if (pos < NODE_CAP)
                lbkt[nd * BROW + pos] = (unsigned short)(pr & 0xffffu);
        }
    }
    ((float4*)mbuf)[tid] = mrow_ld;      // merge tile -> LDS (pre-barrier)
    __syncthreads();

    // ---- gather: group G -> node G>>1, parity G&1; lane ln=tid&7 ----------
    int dg = lcur[node];
    int dgc = dg < NODE_CAP ? dg : NODE_CAP;

    const uint2* idxp = (const uint2*)(lbkt + node * BROW + par * 4);
    uint2 iw0 = idxp[0], iw1 = idxp[2], iw2 = idxp[4], iw3 = idxp[6];

    float af[4][8];
#pragma unroll
    for (int ch = 0; ch < 4; ch++)
#pragma unroll
        for (int k = 0; k < 8; k++) af[ch][k] = 0.f;

    {   // fast window: edges 0..15 -- branchless
        unsigned int idx[8]; float m[8];
        unsigned int iww[4] = { iw0.x, iw0.y, iw1.x, iw1.y };
#pragma unroll
        for (int q = 0; q < 4; q++) {
            int e = (q >> 1) * 8 + par * 4 + (q & 1) * 2;
            unsigned int lo = iww[q] & 0xffffu, hi = iww[q] >> 16;
            idx[q * 2]     = e     < dgc ? lo : 0u;
            m[q * 2]       = e     < dgc ? 1.f : 0.f;
            idx[q * 2 + 1] = e + 1 < dgc ? hi : 0u;
            m[q * 2 + 1]   = e + 1 < dgc ? 1.f : 0.f;
        }
        uint4 v[8];
#pragma unroll
        for (int k = 0; k < 8; k++)
            v[k] = *(const uint4*)(data16 + (size_t)idx[k] * D + 8 * ln);
#pragma unroll
        for (int k = 0; k < 8; k++) {
            int ch = k & 3;
            af[ch][0] += m[k] * bflo(v[k].x); af[ch][1] += m[k] * bfhi(v[k].x);
            af[ch][2] += m[k] * bflo(v[k].y); af[ch][3] += m[k] * bfhi(v[k].y);
            af[ch][4] += m[k] * bflo(v[k].z); af[ch][5] += m[k] * bfhi(v[k].z);
            af[ch][6] += m[k] * bflo(v[k].w); af[ch][7] += m[k] * bfhi(v[k].w);
        }
    }
    // its 2..3: coarse group-uniform guard, branchless inside
#pragma unroll
    for (int it = 2; it < 4; it++) {
        int e0 = it * 8 + par * 4;
        if (e0 < dgc) {
            uint2 iw = (it == 2) ? iw2 : iw3;
            unsigned int i0 = iw.x & 0xffffu, i1 = iw.x >> 16;
            unsigned int i2 = iw.y & 0xffffu, i3 = iw.y >> 16;
            unsigned int jdx[4]; float mm[4];
            jdx[0] = i0;                       mm[0] = 1.f;
            jdx[1] = e0 + 1 < dgc ? i1 : 0u;   mm[1] = e0 + 1 < dgc ? 1.f : 0.f;
            jdx[2] = e0 + 2 < dgc ? i2 : 0u;   mm[2] = e0 + 2 < dgc ? 1.f : 0.f;
            jdx[3] = e0 + 3 < dgc ? i3 : 0u;   mm[3] = e0 + 3 < dgc ? 1.f : 0.f;
            uint4 vv[4];
#pragma unroll
            for (int k = 0; k < 4; k++)
                vv[k] = *(const uint4*)(data16 + (size_t)jdx[k] * D + 8 * ln);
#pragma unroll
            for (int k = 0; k < 4; k++) {
                af[k][0] += mm[k] * bflo(vv[k].x); af[k][1] += mm[k] * bfhi(vv[k].x);
                af[k][2] += mm[k] * bflo(vv[k].y); af[k][3] += mm[k] * bfhi(vv[k].y);
                af[k][4] += mm[k] * bflo(vv[k].z); af[k][5] += mm[k] * bfhi(vv[k].z);
                af[k][6] += mm[k] * bflo(vv[k].w); af[k][7] += mm[k] * bfhi(vv[k].w);
            }
        }
    }
    // dynamic tail: deg > 32 (~6 nodes in the whole graph)
    int nIt = (dgc + 7) >> 3;
    for (int it = 4; it < nIt; it++) {
        uint2 iw = idxp[it * 2];
        int e0 = it * 8 + par * 4;
        unsigned int i0 = iw.x & 0xffffu, i1 = iw.x >> 16;
        unsigned int i2 = iw.y & 0xffffu, i3 = iw.y >> 16;
        unsigned int jdx[4]; float mm[4];
        jdx[0] = e0     < dgc ? i0 : 0u;   mm[0] = e0     < dgc ? 1.f : 0.f;
        jdx[1] = e0 + 1 < dgc ? i1 : 0u;   mm[1] = e0 + 1 < dgc ? 1.f : 0.f;
        jdx[2] = e0 + 2 < dgc ? i2 : 0u;   mm[2] = e0 + 2 < dgc ? 1.f : 0.f;
        jdx[3] = e0 + 3 < dgc ? i3 : 0u;   mm[3] = e0 + 3 < dgc ? 1.f : 0.f;
        uint4 vv[4];
#pragma unroll
        for (int k = 0; k < 4; k++)
            vv[k] = *(const uint4*)(data16 + (size_t)jdx[k] * D + 8 * ln);
#pragma unroll
        for (int k = 0; k < 4; k++) {
            af[k][0] += mm[k] * bflo(vv[k].x); af[k][1] += mm[k] * bfhi(vv[k].x);
            af[k][2] += mm[k] * bflo(vv[k].y); af[k][3] += mm[k] * bfhi(vv[k].y);
            af[k][4] += mm[k] * bflo(vv[k].z); af[k][5] += mm[k] * bfhi(vv[k].z);
            af[k][6] += mm[k] * bflo(vv[k].w); af[k][7] += mm[k] * bfhi(vv[k].w);
        }
    }

    float sv[8];
#pragma unroll
    for (int k = 0; k < 8; k++)
        sv[k] = (af[0][k] + af[1][k]) + (af[2][k] + af[3][k]);
#pragma unroll
    for (int k = 0; k < 8; k++) sv[k] += __shfl_xor(sv[k], 8);   // parities

    if (par == 0) {
        float inv = dg > 0 ? 1.0f / (float)dg : 0.0f;
        float msk = dg > 0 ? 1.0f : 0.0f;
        float4 h0, h1;
        h0.x = (o0.x - sv[0] * inv) * msk; h0.y = (o0.y - sv[1] * inv) * msk;
        h0.z = (o0.z - sv[2] * inv) * msk; h0.w = (o0.w - sv[3] * inv) * msk;
        h1.x = (o1.x - sv[4] * inv) * msk; h1.y = (o1.y - sv[5] * inv) * msk;
        h1.z = (o1.z - sv[6] * inv) * msk; h1.w = (o1.w - sv[7] * inv) * msk;
        float4* hp = (float4*)(hbuf + node * D + 8 * ln);
        hp[0] = h0; hp[1] = h1;
    }
    __syncthreads();

    // ---- epilogue GEMVs: wave w -> nodes 4w..4w+3 -------------------------
    // pass 1: acc = b_tr + m @ W_tr^T   (one 64-VGPR fragment set, reused)
    int w = tid >> 6;
    float acc[4];
    {
        float4 Wr[16];
        const float4* wrow = (const float4*)(W_tr + (size_t)lane * D);
#pragma unroll
        for (int i = 0; i < 16; i++) Wr[i] = wrow[i];
#pragma unroll
        for (int tg = 0; tg < 4; tg++) {
            int t = w * 4 + tg;
            const float4* mrow = (const float4*)(mbuf + t * D);
            float a = bias;
#pragma unroll
            for (int i = 0; i < 16; i++) {
                float4 mq = mrow[i];        // same addr across wave -> broadcast
                a += mq.x * Wr[i].x + mq.y * Wr[i].y
                   + mq.z * Wr[i].z + mq.w * Wr[i].w;
            }
            acc[tg] = a;
        }
    }
    // pass 2: acc += h @ W_lin^T; relu; single out write
    {
        float4 Wr[16];
        const float4* wrow = (const float4*)(W_lin + (size_t)lane * D);
#pragma unroll
        for (int i = 0; i < 16; i++) Wr[i] = wrow[i];
#pragma unroll
        for (int tg = 0; tg < 4; tg++) {
            int t = w * 4 + tg;
            int nn = nodeBase + t;
            const float4* hrow = (const float4*)(hbuf + t * D);
            float a = acc[tg];
#pragma unroll
            for (int i = 0; i < 16; i++) {
                float4 hq = hrow[i];        // broadcast read
                a += hq.x * Wr[i].x + hq.y * Wr[i].y
                   + hq.z * Wr[i].z + hq.w * Wr[i].w;
            }
            out[(size_t)nn * D + lane] = a > 0.f ? a : 0.f;
        }
    }
}

extern "C" void kernel_launch(void* const* d_in, const int* in_sizes, int n_in,
                              void* d_out, int out_size, void* d_ws, size_t ws_size,
                              hipStream_t stream) {
    const float* data  = (const float*)d_in[0];
    const float* merge = (const float*)d_in[1];
    const int*   src   = (const int*)d_in[2];
    const int*   tgt   = (const int*)d_in[3];
    // d_in[4]=W_lin, d_in[5]=b_lin (cancels in lap), d_in[6]=W_tr, d_in[7]=b_tr
    const float* W_lin = (const float*)d_in[4];
    const float* W_tr  = (const float*)d_in[6];
    const float* b_tr  = (const float*)d_in[7];
    float* out = (float*)d_out;

    // Workspace: gCur[256 i32] | gPairs[196*CCAP u32] (3.5 MB)
    //            | data16[N*D bf16] (6.4 MB)            total ~10 MB
    char* ws = (char*)d_ws;
    size_t o = 0;
    int*            gCur   = (int*)(ws + o);            o += 256 * 4;
    unsigned int*   gPairs = (unsigned int*)(ws + o);   o += (size_t)COARSE * CCAP * 4;
    unsigned short* data16 = (unsigned short*)(ws + o); o += (size_t)N_NODES * D * 2;

    hipMemsetAsync(gCur, 0, 256 * 4, stream);

    k1_kernel<<<K1_BLOCKS, 256, 0, stream>>>(
        data, src, tgt, data16, gCur, gPairs);

    k2_kernel<<<BINS, 256, 0, stream>>>(
        data, merge, data16, gCur, gPairs, W_lin, W_tr, b_tr, out);
}

// Round 7
// 151.505 us; speedup vs baseline: 2.7507x; 1.1522x over previous
//
#include <hip/hip_runtime.h>

#define N_NODES 50000
#define N_EDGES 800000
#define D 64
#define KBINS 782            // 64-node bins (tgt>>6); 782*64 = 50048 >= N
#define CCAP64 1280          // edges/bin: mean 1024, sigma 32 -> +8 sigma
#define BIN_NODES 64         // k2 nodes per block
#define NODE_CAP 64          // deg ~ Poisson(16); P(>64) ~ 1e-18
#define BROW 72              // u16 stride per node bucket in LDS (144 B)
#define KA_BLOCKS 391        // 2048 edges per block (last: 1280)
#define KA_EDGES 2048
#define GEMV_BLOCKS 3125     // 16 rows per block (merge@W_tr^T role)
#define CVT_BLOCKS 3125
#define K1_BLOCKS (KA_BLOCKS + GEMV_BLOCKS + CVT_BLOCKS)
#define SCAN_W 5             // ceil(CCAP64/256) scan words per thread

__device__ __forceinline__ unsigned int f2bf(float f) {
    unsigned int u = __builtin_bit_cast(unsigned int, f);
    return (u + 0x7fffu + ((u >> 16) & 1u)) >> 16;
}
__device__ __forceinline__ float bflo(unsigned int v) {
    return __builtin_bit_cast(float, v << 16);
}
__device__ __forceinline__ float bfhi(unsigned int v) {
    return __builtin_bit_cast(float, v & 0xffff0000u);
}

// ---------------------------------------------------------------------------
// ROUND-18 (resubmit -- R6 bench was an infra failure, experiment never ran).
// Revert R5's GEMV move (out write-once bought no HBM traffic -- FETCH
// +1.3MB only -- while doubling the epilogue's broadcast-ds_read cost ON the
// critical path; in k1 the GEMV runs free behind KA's long pole).
// New change: KA bins at 64-NODE granularity (tgt>>6, 782 bins, hist 9.4KB
// LDS) so each k2 block's bin is exactly its own 64 nodes:
//   scan 18->5 loads, filter pass ELIMINATED (every edge belongs),
//   gPairs read once instead of 16x.
// Cost accepted in KA: ~724 reserve atomics/block (vs 196), scatter runs
// ~2.6 entries (worse coalescing, ~+7MB writes).
// ---------------------------------------------------------------------------
__global__ __launch_bounds__(256) void k1_kernel(
        const float* __restrict__ data,
        const float* __restrict__ merge,
        const int* __restrict__ src, const int* __restrict__ tgt,
        const float* __restrict__ W_tr, const float* __restrict__ b_tr,
        unsigned short* __restrict__ data16,
        int* __restrict__ gCur, unsigned int* __restrict__ gPairs,
        float* __restrict__ outv) {
    __shared__ __align__(16) unsigned int epair[KA_EDGES];   // 8 KB
    __shared__ int hist[KBINS], rbase[KBINS], cur2[KBINS];   // 9.4 KB
    int b = blockIdx.x;
    int tid = threadIdx.x;
    if (b < KA_BLOCKS) {
        int eb = b * KA_EDGES;
        int n = N_EDGES - eb; if (n > KA_EDGES) n = KA_EDGES;
        for (int i = tid; i < KBINS; i += 256) { hist[i] = 0; cur2[i] = 0; }
        __syncthreads();
        for (int i = tid; i < n; i += 256) {
            int t = tgt[eb + i];
            unsigned int p = ((unsigned int)t << 16) | (unsigned int)src[eb + i];
            epair[i] = p;
            atomicAdd(&hist[t >> 6], 1);
        }
        __syncthreads();
        for (int i = tid; i < KBINS; i += 256)
            if (hist[i] > 0)
                rbase[i] = atomicAdd(&gCur[i], hist[i]);
        __syncthreads();
        for (int i = tid; i < n; i += 256) {
            unsigned int p = epair[i];
            int c = p >> 22;                        // tgt>>6
            int pos = rbase[c] + atomicAdd(&cur2[c], 1);
            if (pos < CCAP64) gPairs[(size_t)c * CCAP64 + pos] = p;
        }
    } else if (b < KA_BLOCKS + GEMV_BLOCKS) {
        int gb = b - KA_BLOCKS;
        int lane = tid & 63;
        float* mtile = (float*)epair;               // 4 KB alias
        float4 Wr[16];
        const float4* wrow = (const float4*)(W_tr + (size_t)lane * D);
#pragma unroll
        for (int i = 0; i < 16; i++) Wr[i] = wrow[i];
        float bias = b_tr[lane];
        // stage 16 contiguous rows (4 KB) coalesced: thread tid -> 16 B
        ((float4*)mtile)[tid] =
            ((const float4*)(merge + (size_t)gb * 16 * D))[tid];
        __syncthreads();
        int w = tid >> 6;
#pragma unroll
        for (int tg = 0; tg < 4; tg++) {
            int t = w * 4 + tg;
            const float4* hrow = (const float4*)(mtile + t * D);
            float acc = bias;
#pragma unroll
            for (int i = 0; i < 16; i++) {
                float4 hq = hrow[i];                // broadcast read
                acc += hq.x * Wr[i].x + hq.y * Wr[i].y
                     + hq.z * Wr[i].z + hq.w * Wr[i].w;
            }
            outv[(size_t)(gb * 16 + t) * D + lane] = acc;
        }
    } else {
        int i = (b - KA_BLOCKS - GEMV_BLOCKS) * 256 + tid;   // float4 index
        float4 d = ((const float4*)data)[i];
        uint2 v;
        v.x = f2bf(d.x) | (f2bf(d.y) << 16);
        v.y = f2bf(d.z) | (f2bf(d.w) << 16);
        ((uint2*)data16)[i] = v;
    }
}

// ---------------------------------------------------------------------------
// K2: one block per 64-node bin (782 blocks, all co-resident at ~3/CU).
//  1. scan own bin: 5 unconditional clamped loads; NO filter -- every edge
//     belongs; append src to per-node LDS buckets.
//  2. gather: 32 groups of 8 lanes; group g -> parity g&1, nodes
//     {q*16 + (g>>1)} for q=0..3 (4 sequential tasks). Branchless fast
//     window 0..15, coarse-guarded 16..31, dynamic tail.
//  3. epilogue: wave w -> nodes w*16..w*16+15; out += h@W_lin^T, relu.
//     Wr fragment + oldv prefetched before the hbuf barrier.
// ---------------------------------------------------------------------------
__global__ __launch_bounds__(256) void k2_kernel(
        const float* __restrict__ data,
        const unsigned short* __restrict__ data16,
        const int* __restrict__ gCur,
        const unsigned int* __restrict__ gPairs,
        const float* __restrict__ W_lin,
        float* __restrict__ out) {
    __shared__ __align__(16) unsigned short lbkt[BIN_NODES * BROW];  // 9 KB
    __shared__ int lcur[BIN_NODES];
    __shared__ float hbuf[BIN_NODES * D];                            // 16 KB

    int tid = threadIdx.x;
    int lane = tid & 63;
    int bin = blockIdx.x;
    int nodeBase = bin * BIN_NODES;

    if (tid < BIN_NODES) lcur[tid] = 0;
    __syncthreads();

    // ---- scan: own bin, unconditional clamped loads, no filter ------------
    int cnt = gCur[bin]; if (cnt > CCAP64) cnt = CCAP64;
    const unsigned int* cp = gPairs + (size_t)bin * CCAP64;
    unsigned int pw[SCAN_W];
#pragma unroll
    for (int j = 0; j < SCAN_W; j++) {
        int i = j * 256 + tid;
        pw[j] = cp[i < cnt ? i : 0];
    }
#pragma unroll
    for (int j = 0; j < SCAN_W; j++) {
        int i = j * 256 + tid;
        unsigned int pr = pw[j];
        if (i < cnt) {
            int nd = (pr >> 16) & 63;            // local node within bin
            int pos = atomicAdd(&lcur[nd], 1);
            if (pos < NODE_CAP)
                lbkt[nd * BROW + pos] = (unsigned short)(pr & 0xffffu);
        }
    }
    __syncthreads();

    // ---- gather: group g=tid>>3 (0..31), lane ln=tid&7, par=g&1 -----------
    int g = tid >> 3;
    int ln = tid & 7;
    int par = g & 1;
    int nsel = g >> 1;                           // 0..15

#pragma unroll 1
    for (int q = 0; q < 4; q++) {
        int node = q * 16 + nsel;                // 0..63
        int n = nodeBase + node;
        int valid = n < N_NODES;
        int dg = lcur[node];
        int dgc = dg < NODE_CAP ? dg : NODE_CAP;

        const float4* orow = (const float4*)(data + (size_t)(valid ? n : 0) * D + 8 * ln);
        float4 o0 = orow[0], o1 = orow[1];

        const uint2* idxp = (const uint2*)(lbkt + node * BROW + par * 4);
        uint2 iw0 = idxp[0], iw1 = idxp[2], iw2 = idxp[4], iw3 = idxp[6];

        float af[4][8];
#pragma unroll
        for (int ch = 0; ch < 4; ch++)
#pragma unroll
            for (int k = 0; k < 8; k++) af[ch][k] = 0.f;

        {   // fast window: edges 0..15 -- branchless
            unsigned int idx[8]; float m[8];
            unsigned int iww[4] = { iw0.x, iw0.y, iw1.x, iw1.y };
#pragma unroll
            for (int qq = 0; qq < 4; qq++) {
                int e = (qq >> 1) * 8 + par * 4 + (qq & 1) * 2;
                unsigned int lo = iww[qq] & 0xffffu, hi = iww[qq] >> 16;
                idx[qq * 2]     = e     < dgc ? lo : 0u;
                m[qq * 2]       = e     < dgc ? 1.f : 0.f;
                idx[qq * 2 + 1] = e + 1 < dgc ? hi : 0u;
                m[qq * 2 + 1]   = e + 1 < dgc ? 1.f : 0.f;
            }
            uint4 v[8];
#pragma unroll
            for (int k = 0; k < 8; k++)
                v[k] = *(const uint4*)(data16 + (size_t)idx[k] * D + 8 * ln);
#pragma unroll
            for (int k = 0; k < 8; k++) {
                int ch = k & 3;
                af[ch][0] += m[k] * bflo(v[k].x); af[ch][1] += m[k] * bfhi(v[k].x);
                af[ch][2] += m[k] * bflo(v[k].y); af[ch][3] += m[k] * bfhi(v[k].y);
                af[ch][4] += m[k] * bflo(v[k].z); af[ch][5] += m[k] * bfhi(v[k].z);
                af[ch][6] += m[k] * bflo(v[k].w); af[ch][7] += m[k] * bfhi(v[k].w);
            }
        }
        // its 2..3: coarse group-uniform guard, branchless inside
#pragma unroll
        for (int it = 2; it < 4; it++) {
            int e0 = it * 8 + par * 4;
            if (e0 < dgc) {
                uint2 iw = (it == 2) ? iw2 : iw3;
                unsigned int i0 = iw.x & 0xffffu, i1 = iw.x >> 16;
                unsigned int i2 = iw.y & 0xffffu, i3 = iw.y >> 16;
                unsigned int jdx[4]; float mm[4];
                jdx[0] = i0;                       mm[0] = 1.f;
                jdx[1] = e0 + 1 < dgc ? i1 : 0u;   mm[1] = e0 + 1 < dgc ? 1.f : 0.f;
                jdx[2] = e0 + 2 < dgc ? i2 : 0u;   mm[2] = e0 + 2 < dgc ? 1.f : 0.f;
                jdx[3] = e0 + 3 < dgc ? i3 : 0u;   mm[3] = e0 + 3 < dgc ? 1.f : 0.f;
                uint4 vv[4];
#pragma unroll
                for (int k = 0; k < 4; k++)
                    vv[k] = *(const uint4*)(data16 + (size_t)jdx[k] * D + 8 * ln);
#pragma unroll
                for (int k = 0; k < 4; k++) {
                    af[k][0] += mm[k] * bflo(vv[k].x); af[k][1] += mm[k] * bfhi(vv[k].x);
                    af[k][2] += mm[k] * bflo(vv[k].y); af[k][3] += mm[k] * bfhi(vv[k].y);
                    af[k][4] += mm[k] * bflo(vv[k].z); af[k][5] += mm[k] * bfhi(vv[k].z);
                    af[k][6] += mm[k] * bflo(vv[k].w); af[k][7] += mm[k] * bfhi(vv[k].w);
                }
            }
        }
        // dynamic tail: deg > 32 (~6 nodes in the whole graph)
        int nIt = (dgc + 7) >> 3;
        for (int it = 4; it < nIt; it++) {
            uint2 iw = idxp[it * 2];
            int e0 = it * 8 + par * 4;
            unsigned int i0 = iw.x & 0xffffu, i1 = iw.x >> 16;
            unsigned int i2 = iw.y & 0xffffu, i3 = iw.y >> 16;
            unsigned int jdx[4]; float mm[4];
            jdx[0] = e0     < dgc ? i0 : 0u;   mm[0] = e0     < dgc ? 1.f : 0.f;
            jdx[1] = e0 + 1 < dgc ? i1 : 0u;   mm[1] = e0 + 1 < dgc ? 1.f : 0.f;
            jdx[2] = e0 + 2 < dgc ? i2 : 0u;   mm[2] = e0 + 2 < dgc ? 1.f : 0.f;
            jdx[3] = e0 + 3 < dgc ? i3 : 0u;   mm[3] = e0 + 3 < dgc ? 1.f : 0.f;
            uint4 vv[4];
#pragma unroll
            for (int k = 0; k < 4; k++)
                vv[k] = *(const uint4*)(data16 + (size_t)jdx[k] * D + 8 * ln);
#pragma unroll
            for (int k = 0; k < 4; k++) {
                af[k][0] += mm[k] * bflo(vv[k].x); af[k][1] += mm[k] * bfhi(vv[k].x);
                af[k][2] += mm[k] * bflo(vv[k].y); af[k][3] += mm[k] * bfhi(vv[k].y);
                af[k][4] += mm[k] * bflo(vv[k].z); af[k][5] += mm[k] * bfhi(vv[k].z);
                af[k][6] += mm[k] * bflo(vv[k].w); af[k][7] += mm[k] * bfhi(vv[k].w);
            }
        }

        float sv[8];
#pragma unroll
        for (int k = 0; k < 8; k++)
            sv[k] = (af[0][k] + af[1][k]) + (af[2][k] + af[3][k]);
#pragma unroll
        for (int k = 0; k < 8; k++) sv[k] += __shfl_xor(sv[k], 8);   // parities

        if (par == 0) {
            float inv = dg > 0 ? 1.0f / (float)dg : 0.0f;
            float msk = dg > 0 ? 1.0f : 0.0f;
            float4 h0, h1;
            h0.x = (o0.x - sv[0] * inv) * msk; h0.y = (o0.y - sv[1] * inv) * msk;
            h0.z = (o0.z - sv[2] * inv) * msk; h0.w = (o0.w - sv[3] * inv) * msk;
            h1.x = (o1.x - sv[4] * inv) * msk; h1.y = (o1.y - sv[5] * inv) * msk;
            h1.z = (o1.z - sv[6] * inv) * msk; h1.w = (o1.w - sv[7] * inv) * msk;
            float4* hp = (float4*)(hbuf + node * D + 8 * ln);
            hp[0] = h0; hp[1] = h1;
        }
    }

    // ---- GEMV operand prefetch: latency hidden under the barrier ----------
    float4 Wr[16];
    const float4* wrow = (const float4*)(W_lin + (size_t)lane * D);
#pragma unroll
    for (int i = 0; i < 16; i++) Wr[i] = wrow[i];
    int w = tid >> 6;
    float oldv[16];
#pragma unroll
    for (int u = 0; u < 16; u++) {
        int nn = nodeBase + w * 16 + u;
        oldv[u] = out[(size_t)(nn < N_NODES ? nn : 0) * D + lane];
    }
    __syncthreads();

    // ---- fused GEMV: wave w -> nodes w*16..w*16+15; out += h@W_lin^T ------
#pragma unroll 1
    for (int u = 0; u < 16; u++) {
        int t = w * 16 + u;
        int nn = nodeBase + t;
        const float4* hrow = (const float4*)(hbuf + t * D);
        float acc = 0.f;
#pragma unroll
        for (int i = 0; i < 16; i++) {
            float4 hq = hrow[i];            // same addr across wave -> broadcast
            acc += hq.x * Wr[i].x + hq.y * Wr[i].y
                 + hq.z * Wr[i].z + hq.w * Wr[i].w;
        }
        float o = acc + oldv[u];
        if (nn < N_NODES)
            out[(size_t)nn * D + lane] = o > 0.f ? o : 0.f;
    }
}

extern "C" void kernel_launch(void* const* d_in, const int* in_sizes, int n_in,
                              void* d_out, int out_size, void* d_ws, size_t ws_size,
                              hipStream_t stream) {
    const float* data  = (const float*)d_in[0];
    const float* merge = (const float*)d_in[1];
    const int*   src   = (const int*)d_in[2];
    const int*   tgt   = (const int*)d_in[3];
    // d_in[4]=W_lin, d_in[5]=b_lin (cancels in lap), d_in[6]=W_tr, d_in[7]=b_tr
    const float* W_lin = (const float*)d_in[4];
    const float* W_tr  = (const float*)d_in[6];
    const float* b_tr  = (const float*)d_in[7];
    float* out = (float*)d_out;

    // Workspace: gCur[1024 i32] | gPairs[782*1280 u32] (4.0 MB)
    //            | data16[N*D bf16] (6.4 MB)            total ~10.4 MB
    char* ws = (char*)d_ws;
    size_t o = 0;
    int*            gCur   = (int*)(ws + o);            o += 1024 * 4;
    unsigned int*   gPairs = (unsigned int*)(ws + o);   o += (size_t)KBINS * CCAP64 * 4;
    unsigned short* data16 = (unsigned short*)(ws + o); o += (size_t)N_NODES * D * 2;

    hipMemsetAsync(gCur, 0, KBINS * 4, stream);

    k1_kernel<<<K1_BLOCKS, 256, 0, stream>>>(
        data, merge, src, tgt, W_tr, b_tr, data16, gCur, gPairs, out);

    k2_kernel<<<KBINS, 256, 0, stream>>>(
        data, data16, gCur, gPairs, W_lin, out);
}

// Round 8
// 139.394 us; speedup vs baseline: 2.9896x; 1.0869x over previous
//
#include <hip/hip_runtime.h>

#define N_NODES 50000
#define N_EDGES 800000
#define D 64
#define KBINS 782            // 64-node bins (tgt>>6); 782*64 = 50048 >= N
#define CCAP64 1280          // edges/bin: mean 1024, sigma 32 -> +8 sigma
#define BIN_NODES 64         // k2 nodes per block
#define NODE_CAP 64          // deg ~ Poisson(16); P(>64) ~ 1e-18
#define BROW 72              // u16 stride per node bucket in LDS (144 B)
#define KA_BLOCKS 391        // 2048 edges per block (last: 1280)
#define KA_EDGES 2048
#define GEMV_BLOCKS 782      // 64 rows per block (merge@W_tr^T via MFMA)
#define CVT_BLOCKS 3125
#define K1_BLOCKS (KA_BLOCKS + GEMV_BLOCKS + CVT_BLOCKS)
#define SCAN_W 5             // ceil(CCAP64/256) scan words per thread

typedef __attribute__((ext_vector_type(8))) short short8t;   // 8 bf16 (4 VGPR)
typedef __attribute__((ext_vector_type(4))) float f32x4;     // MFMA acc

__device__ __forceinline__ unsigned int f2bf(float f) {
    unsigned int u = __builtin_bit_cast(unsigned int, f);
    return (u + 0x7fffu + ((u >> 16) & 1u)) >> 16;
}
__device__ __forceinline__ float bflo(unsigned int v) {
    return __builtin_bit_cast(float, v << 16);
}
__device__ __forceinline__ float bfhi(unsigned int v) {
    return __builtin_bit_cast(float, v & 0xffff0000u);
}
__device__ __forceinline__ short8t pack8(float4 a, float4 b) {
    union { uint4 u; short8t s; } cv;
    cv.u.x = f2bf(a.x) | (f2bf(a.y) << 16);
    cv.u.y = f2bf(a.z) | (f2bf(a.w) << 16);
    cv.u.z = f2bf(b.x) | (f2bf(b.y) << 16);
    cv.u.w = f2bf(b.z) | (f2bf(b.w) << 16);
    return cv.s;
}
// LDS bf16 tile [64 rows][64 cols] (128 B/row) with XOR swizzle (G4: row-major
// 128B rows are a 16-way conflict on column-slice ds_read_b128; identical XOR
// on write+read makes it ~2-way = free). kb = 16-byte block offset in the row.
__device__ __forceinline__ short8t ld_tile(const unsigned short* t, int row, int kb) {
    int addr = (row * 128 + kb) ^ ((row & 7) << 4);
    union { uint4 u; short8t s; } cv;
    cv.u = *(const uint4*)((const char*)t + addr);
    return cv.s;
}
__device__ __forceinline__ void st_tile(unsigned short* t, int row, int kb, uint4 v) {
    int addr = (row * 128 + kb) ^ ((row & 7) << 4);
    *(uint4*)((char*)t + addr) = v;
}

// ---------------------------------------------------------------------------
// ROUND-19: both GEMVs -> MFMA. The two broadcast-ds_read GEMVs cost ~15.6 us
// of LDS-pipe time EACH (256 ds_read_b128 + 256 FMA per wave; R5 proved the
// cost is on the critical path when moved). MFMA replaces that with 2 A-frag
// ds_reads + 8 mfma_f32_16x16x32_bf16 per wave per 64-row tile.
// Layout safety: A/B share one k-bijection (contraction is position-paired,
// so any consistent packing is correct); C/D uses the HW-verified map
// col=lane&15, row=(lane>>4)*4+reg (m89/m91). Tiles XOR-swizzled.
// Precision: bf16 merge/h/W adds ~0.02-0.03 absmax (threshold 0.0887).
// ---------------------------------------------------------------------------
__global__ __launch_bounds__(256) void k1_kernel(
        const float* __restrict__ data,
        const float* __restrict__ merge,
        const int* __restrict__ src, const int* __restrict__ tgt,
        const float* __restrict__ W_tr, const float* __restrict__ b_tr,
        unsigned short* __restrict__ data16,
        int* __restrict__ gCur, unsigned int* __restrict__ gPairs,
        float* __restrict__ outv) {
    __shared__ __align__(16) unsigned int epair[KA_EDGES];   // 8 KB
    __shared__ int hist[KBINS], rbase[KBINS], cur2[KBINS];   // 9.4 KB
    int b = blockIdx.x;
    int tid = threadIdx.x;
    if (b < KA_BLOCKS) {
        int eb = b * KA_EDGES;
        int n = N_EDGES - eb; if (n > KA_EDGES) n = KA_EDGES;
        for (int i = tid; i < KBINS; i += 256) { hist[i] = 0; cur2[i] = 0; }
        __syncthreads();
        for (int i = tid; i < n; i += 256) {
            int t = tgt[eb + i];
            unsigned int p = ((unsigned int)t << 16) | (unsigned int)src[eb + i];
            epair[i] = p;
            atomicAdd(&hist[t >> 6], 1);
        }
        __syncthreads();
        for (int i = tid; i < KBINS; i += 256)
            if (hist[i] > 0)
                rbase[i] = atomicAdd(&gCur[i], hist[i]);
        __syncthreads();
        for (int i = tid; i < n; i += 256) {
            unsigned int p = epair[i];
            int c = p >> 22;                        // tgt>>6
            int pos = rbase[c] + atomicAdd(&cur2[c], 1);
            if (pos < CCAP64) gPairs[(size_t)c * CCAP64 + pos] = p;
        }
    } else if (b < KA_BLOCKS + GEMV_BLOCKS) {
        // ---- skip GEMM: out[64 rows] = merge@W_tr^T + b_tr (MFMA) ---------
        int gb = b - KA_BLOCKS;
        int lane = tid & 63;
        int w = tid >> 6;
        int rowBase = gb * 64;
        unsigned short* mt = (unsigned short*)epair;   // bf16 tile [64][64], 8 KB

        // stage merge tile -> bf16 LDS (swizzled): thread (r=tid>>2, q=tid&3)
        {
            int r = tid >> 2, q = tid & 3;
            int gr = rowBase + r; if (gr >= N_NODES) gr = N_NODES - 1;
            const float4* mp = (const float4*)(merge + (size_t)gr * D + q * 16);
            float4 f0 = mp[0], f1 = mp[1], f2 = mp[2], f3 = mp[3];
            union { short8t s; uint4 u; } c0, c1;
            c0.s = pack8(f0, f1); c1.s = pack8(f2, f3);
            st_tile(mt, r, q * 32, c0.u);
            st_tile(mt, r, q * 32 + 16, c1.u);
        }
        // B-frags: W_tr rows 16t+(lane&15), k floats (lane>>4)*8 + s*32
        short8t bfr[4][2];
        float bias[4];
#pragma unroll
        for (int t = 0; t < 4; t++) {
            int wrow = 16 * t + (lane & 15);
            bias[t] = b_tr[wrow];
#pragma unroll
            for (int s = 0; s < 2; s++) {
                const float4* wp = (const float4*)(W_tr + (size_t)wrow * D
                                                   + (lane >> 4) * 8 + s * 32);
                bfr[t][s] = pack8(wp[0], wp[1]);
            }
        }
        __syncthreads();

        f32x4 acc[4] = {{0,0,0,0},{0,0,0,0},{0,0,0,0},{0,0,0,0}};
#pragma unroll
        for (int s = 0; s < 2; s++) {
            short8t a = ld_tile(mt, 16 * w + (lane & 15),
                                (lane >> 4) * 16 + s * 64);
#pragma unroll
            for (int t = 0; t < 4; t++)
                acc[t] = __builtin_amdgcn_mfma_f32_16x16x32_bf16(
                    a, bfr[t][s], acc[t], 0, 0, 0);
        }
        // C/D: row=(lane>>4)*4+j (node within strip), col=lane&15
#pragma unroll
        for (int t = 0; t < 4; t++) {
            int cl = 16 * t + (lane & 15);
#pragma unroll
            for (int j = 0; j < 4; j++) {
                int node = rowBase + 16 * w + (lane >> 4) * 4 + j;
                if (node < N_NODES)
                    outv[(size_t)node * D + cl] = acc[t][j] + bias[t];
            }
        }
    } else {
        int i = (b - KA_BLOCKS - GEMV_BLOCKS) * 256 + tid;   // float4 index
        float4 d = ((const float4*)data)[i];
        uint2 v;
        v.x = f2bf(d.x) | (f2bf(d.y) << 16);
        v.y = f2bf(d.z) | (f2bf(d.w) << 16);
        ((uint2*)data16)[i] = v;
    }
}

// ---------------------------------------------------------------------------
// K2: one block per 64-node bin. Scan (no filter) -> LDS buckets -> gather
// (branchless windows) -> h rows packed bf16 into swizzled tile -> MFMA
// epilogue: out = relu(h@W_lin^T + out_skip).
// ---------------------------------------------------------------------------
__global__ __launch_bounds__(256) void k2_kernel(
        const float* __restrict__ data,
        const unsigned short* __restrict__ data16,
        const int* __restrict__ gCur,
        const unsigned int* __restrict__ gPairs,
        const float* __restrict__ W_lin,
        float* __restrict__ out) {
    __shared__ __align__(16) unsigned short lbkt[BIN_NODES * BROW];  // 9 KB
    __shared__ int lcur[BIN_NODES];
    __shared__ __align__(16) unsigned short hb[BIN_NODES * D];       // 8 KB bf16

    int tid = threadIdx.x;
    int lane = tid & 63;
    int bin = blockIdx.x;
    int nodeBase = bin * BIN_NODES;

    if (tid < BIN_NODES) lcur[tid] = 0;
    __syncthreads();

    // ---- scan: own bin, unconditional clamped loads, no filter ------------
    int cnt = gCur[bin]; if (cnt > CCAP64) cnt = CCAP64;
    const unsigned int* cp = gPairs + (size_t)bin * CCAP64;
    unsigned int pw[SCAN_W];
#pragma unroll
    for (int j = 0; j < SCAN_W; j++) {
        int i = j * 256 + tid;
        pw[j] = cp[i < cnt ? i : 0];
    }
#pragma unroll
    for (int j = 0; j < SCAN_W; j++) {
        int i = j * 256 + tid;
        unsigned int pr = pw[j];
        if (i < cnt) {
            int nd = (pr >> 16) & 63;            // local node within bin
            int pos = atomicAdd(&lcur[nd], 1);
            if (pos < NODE_CAP)
                lbkt[nd * BROW + pos] = (unsigned short)(pr & 0xffffu);
        }
    }
    __syncthreads();

    // ---- gather: group g=tid>>3 (0..31), lane ln=tid&7, par=g&1 -----------
    int g = tid >> 3;
    int ln = tid & 7;
    int par = g & 1;
    int nsel = g >> 1;                           // 0..15

#pragma unroll 1
    for (int q = 0; q < 4; q++) {
        int node = q * 16 + nsel;                // 0..63
        int n = nodeBase + node;
        int valid = n < N_NODES;
        int dg = lcur[node];
        int dgc = dg < NODE_CAP ? dg : NODE_CAP;

        const float4* orow = (const float4*)(data + (size_t)(valid ? n : 0) * D + 8 * ln);
        float4 o0 = orow[0], o1 = orow[1];

        const uint2* idxp = (const uint2*)(lbkt + node * BROW + par * 4);
        uint2 iw0 = idxp[0], iw1 = idxp[2], iw2 = idxp[4], iw3 = idxp[6];

        float af[4][8];
#pragma unroll
        for (int ch = 0; ch < 4; ch++)
#pragma unroll
            for (int k = 0; k < 8; k++) af[ch][k] = 0.f;

        {   // fast window: edges 0..15 -- branchless
            unsigned int idx[8]; float m[8];
            unsigned int iww[4] = { iw0.x, iw0.y, iw1.x, iw1.y };
#pragma unroll
            for (int qq = 0; qq < 4; qq++) {
                int e = (qq >> 1) * 8 + par * 4 + (qq & 1) * 2;
                unsigned int lo = iww[qq] & 0xffffu, hi = iww[qq] >> 16;
                idx[qq * 2]     = e     < dgc ? lo : 0u;
                m[qq * 2]       = e     < dgc ? 1.f : 0.f;
                idx[qq * 2 + 1] = e + 1 < dgc ? hi : 0u;
                m[qq * 2 + 1]   = e + 1 < dgc ? 1.f : 0.f;
            }
            uint4 v[8];
#pragma unroll
            for (int k = 0; k < 8; k++)
                v[k] = *(const uint4*)(data16 + (size_t)idx[k] * D + 8 * ln);
#pragma unroll
            for (int k = 0; k < 8; k++) {
                int ch = k & 3;
                af[ch][0] += m[k] * bflo(v[k].x); af[ch][1] += m[k] * bfhi(v[k].x);
                af[ch][2] += m[k] * bflo(v[k].y); af[ch][3] += m[k] * bfhi(v[k].y);
                af[ch][4] += m[k] * bflo(v[k].z); af[ch][5] += m[k] * bfhi(v[k].z);
                af[ch][6] += m[k] * bflo(v[k].w); af[ch][7] += m[k] * bfhi(v[k].w);
            }
        }
        // its 2..3: coarse group-uniform guard, branchless inside
#pragma unroll
        for (int it = 2; it < 4; it++) {
            int e0 = it * 8 + par * 4;
            if (e0 < dgc) {
                uint2 iw = (it == 2) ? iw2 : iw3;
                unsigned int i0 = iw.x & 0xffffu, i1 = iw.x >> 16;
                unsigned int i2 = iw.y & 0xffffu, i3 = iw.y >> 16;
                unsigned int jdx[4]; float mm[4];
                jdx[0] = i0;                       mm[0] = 1.f;
                jdx[1] = e0 + 1 < dgc ? i1 : 0u;   mm[1] = e0 + 1 < dgc ? 1.f : 0.f;
                jdx[2] = e0 + 2 < dgc ? i2 : 0u;   mm[2] = e0 + 2 < dgc ? 1.f : 0.f;
                jdx[3] = e0 + 3 < dgc ? i3 : 0u;   mm[3] = e0 + 3 < dgc ? 1.f : 0.f;
                uint4 vv[4];
#pragma unroll
                for (int k = 0; k < 4; k++)
                    vv[k] = *(const uint4*)(data16 + (size_t)jdx[k] * D + 8 * ln);
#pragma unroll
                for (int k = 0; k < 4; k++) {
                    af[k][0] += mm[k] * bflo(vv[k].x); af[k][1] += mm[k] * bfhi(vv[k].x);
                    af[k][2] += mm[k] * bflo(vv[k].y); af[k][3] += mm[k] * bfhi(vv[k].y);
                    af[k][4] += mm[k] * bflo(vv[k].z); af[k][5] += mm[k] * bfhi(vv[k].z);
                    af[k][6] += mm[k] * bflo(vv[k].w); af[k][7] += mm[k] * bfhi(vv[k].w);
                }
            }
        }
        // dynamic tail: deg > 32 (~6 nodes in the whole graph)
        int nIt = (dgc + 7) >> 3;
        for (int it = 4; it < nIt; it++) {
            uint2 iw = idxp[it * 2];
            int e0 = it * 8 + par * 4;
            unsigned int i0 = iw.x & 0xffffu, i1 = iw.x >> 16;
            unsigned int i2 = iw.y & 0xffffu, i3 = iw.y >> 16;
            unsigned int jdx[4]; float mm[4];
            jdx[0] = e0     < dgc ? i0 : 0u;   mm[0] = e0     < dgc ? 1.f : 0.f;
            jdx[1] = e0 + 1 < dgc ? i1 : 0u;   mm[1] = e0 + 1 < dgc ? 1.f : 0.f;
            jdx[2] = e0 + 2 < dgc ? i2 : 0u;   mm[2] = e0 + 2 < dgc ? 1.f : 0.f;
            jdx[3] = e0 + 3 < dgc ? i3 : 0u;   mm[3] = e0 + 3 < dgc ? 1.f : 0.f;
            uint4 vv[4];
#pragma unroll
            for (int k = 0; k < 4; k++)
                vv[k] = *(const uint4*)(data16 + (size_t)jdx[k] * D + 8 * ln);
#pragma unroll
            for (int k = 0; k < 4; k++) {
                af[k][0] += mm[k] * bflo(vv[k].x); af[k][1] += mm[k] * bfhi(vv[k].x);
                af[k][2] += mm[k] * bflo(vv[k].y); af[k][3] += mm[k] * bfhi(vv[k].y);
                af[k][4] += mm[k] * bflo(vv[k].z); af[k][5] += mm[k] * bfhi(vv[k].z);
                af[k][6] += mm[k] * bflo(vv[k].w); af[k][7] += mm[k] * bfhi(vv[k].w);
            }
        }

        float sv[8];
#pragma unroll
        for (int k = 0; k < 8; k++)
            sv[k] = (af[0][k] + af[1][k]) + (af[2][k] + af[3][k]);
#pragma unroll
        for (int k = 0; k < 8; k++) sv[k] += __shfl_xor(sv[k], 8);   // parities

        if (par == 0) {
            float inv = dg > 0 ? 1.0f / (float)dg : 0.0f;
            float msk = dg > 0 ? 1.0f : 0.0f;
            float4 h0, h1;
            h0.x = (o0.x - sv[0] * inv) * msk; h0.y = (o0.y - sv[1] * inv) * msk;
            h0.z = (o0.z - sv[2] * inv) * msk; h0.w = (o0.w - sv[3] * inv) * msk;
            h1.x = (o1.x - sv[4] * inv) * msk; h1.y = (o1.y - sv[5] * inv) * msk;
            h1.z = (o1.z - sv[6] * inv) * msk; h1.w = (o1.w - sv[7] * inv) * msk;
            // h row -> bf16 tile, cols 8ln..8ln+7 (16-byte block ln), swizzled
            union { short8t s; uint4 u; } hv;
            hv.s = pack8(h0, h1);
            st_tile(hb, node, ln * 16, hv.u);
        }
    }

    // ---- MFMA epilogue operand prefetch (latency hidden under barrier) ----
    int w = tid >> 6;
    short8t bfr[4][2];
#pragma unroll
    for (int t = 0; t < 4; t++)
#pragma unroll
        for (int s = 0; s < 2; s++) {
            const float4* wp = (const float4*)(W_lin
                + (size_t)(16 * t + (lane & 15)) * D + (lane >> 4) * 8 + s * 32);
            bfr[t][s] = pack8(wp[0], wp[1]);
        }
    float oldv[4][4];
#pragma unroll
    for (int t = 0; t < 4; t++) {
        int cl = 16 * t + (lane & 15);
#pragma unroll
        for (int j = 0; j < 4; j++) {
            int node = nodeBase + 16 * w + (lane >> 4) * 4 + j;
            oldv[t][j] = out[(size_t)(node < N_NODES ? node : 0) * D + cl];
        }
    }
    __syncthreads();

    // ---- MFMA: wave w -> rows 16w..16w+15; out = relu(h@W_lin^T + skip) ---
    f32x4 acc[4] = {{0,0,0,0},{0,0,0,0},{0,0,0,0},{0,0,0,0}};
#pragma unroll
    for (int s = 0; s < 2; s++) {
        short8t a = ld_tile(hb, 16 * w + (lane & 15), (lane >> 4) * 16 + s * 64);
#pragma unroll
        for (int t = 0; t < 4; t++)
            acc[t] = __builtin_amdgcn_mfma_f32_16x16x32_bf16(
                a, bfr[t][s], acc[t], 0, 0, 0);
    }
#pragma unroll
    for (int t = 0; t < 4; t++) {
        int cl = 16 * t + (lane & 15);
#pragma unroll
        for (int j = 0; j < 4; j++) {
            int node = nodeBase + 16 * w + (lane >> 4) * 4 + j;
            if (node < N_NODES) {
                float o = acc[t][j] + oldv[t][j];
                out[(size_t)node * D + cl] = o > 0.f ? o : 0.f;
            }
        }
    }
}

extern "C" void kernel_launch(void* const* d_in, const int* in_sizes, int n_in,
                              void* d_out, int out_size, void* d_ws, size_t ws_size,
                              hipStream_t stream) {
    const float* data  = (const float*)d_in[0];
    const float* merge = (const float*)d_in[1];
    const int*   src   = (const int*)d_in[2];
    const int*   tgt   = (const int*)d_in[3];
    // d_in[4]=W_lin, d_in[5]=b_lin (cancels in lap), d_in[6]=W_tr, d_in[7]=b_tr
    const float* W_lin = (const float*)d_in[4];
    const float* W_tr  = (const float*)d_in[6];
    const float* b_tr  = (const float*)d_in[7];
    float* out = (float*)d_out;

    // Workspace: gCur[1024 i32] | gPairs[782*1280 u32] (4.0 MB)
    //            | data16[N*D bf16] (6.4 MB)            total ~10.4 MB
    char* ws = (char*)d_ws;
    size_t o = 0;
    int*            gCur   = (int*)(ws + o);            o += 1024 * 4;
    unsigned int*   gPairs = (unsigned int*)(ws + o);   o += (size_t)KBINS * CCAP64 * 4;
    unsigned short* data16 = (unsigned short*)(ws + o); o += (size_t)N_NODES * D * 2;

    hipMemsetAsync(gCur, 0, KBINS * 4, stream);

    k1_kernel<<<K1_BLOCKS, 256, 0, stream>>>(
        data, merge, src, tgt, W_tr, b_tr, data16, gCur, gPairs, out);

    k2_kernel<<<KBINS, 256, 0, stream>>>(
        data, data16, gCur, gPairs, W_lin, out);
}

// Round 9
// 135.907 us; speedup vs baseline: 3.0664x; 1.0257x over previous
//
#include <hip/hip_runtime.h>

#define N_NODES 50000
#define N_EDGES 800000
#define D 64
#define KBINS 782            // 64-node bins (tgt>>6); 782*64 = 50048 >= N
#define CCAP64 1280          // edges/bin: mean 1024, sigma 32 -> +8 sigma
#define BIN_NODES 64         // k2 nodes per block
#define NODE_CAP 64          // deg ~ Poisson(16); P(>64) ~ 1e-18
#define BROW 72              // u16 stride per node bucket in LDS (144 B)
#define KA_BLOCKS 256        // ONE KA block per CU (800000/256 = 3125 exact)
#define KA_EDGES 3125
#define KA_ITERS 13          // ceil(3125/256)
#define GEMV_BLOCKS 782      // 64 rows per block (merge@W_tr^T via MFMA)
#define CVT_BLOCKS 3125
#define K1_BLOCKS (KA_BLOCKS + GEMV_BLOCKS + CVT_BLOCKS)
#define SCAN_W 5             // ceil(CCAP64/256) scan words per thread

typedef __attribute__((ext_vector_type(8))) short short8t;   // 8 bf16 (4 VGPR)
typedef __attribute__((ext_vector_type(4))) float f32x4;     // MFMA acc

__device__ __forceinline__ unsigned int f2bf(float f) {
    unsigned int u = __builtin_bit_cast(unsigned int, f);
    return (u + 0x7fffu + ((u >> 16) & 1u)) >> 16;
}
__device__ __forceinline__ float bflo(unsigned int v) {
    return __builtin_bit_cast(float, v << 16);
}
__device__ __forceinline__ float bfhi(unsigned int v) {
    return __builtin_bit_cast(float, v & 0xffff0000u);
}
__device__ __forceinline__ short8t pack8(float4 a, float4 b) {
    union { uint4 u; short8t s; } cv;
    cv.u.x = f2bf(a.x) | (f2bf(a.y) << 16);
    cv.u.y = f2bf(a.z) | (f2bf(a.w) << 16);
    cv.u.z = f2bf(b.x) | (f2bf(b.y) << 16);
    cv.u.w = f2bf(b.z) | (f2bf(b.w) << 16);
    return cv.s;
}
// LDS bf16 tile [64 rows][64 cols] (128 B/row) with XOR swizzle (G4: row-major
// 128B rows are a 16-way conflict on column-slice ds_read_b128; identical XOR
// on write+read makes it ~2-way = free). kb = 16-byte block offset in the row.
__device__ __forceinline__ short8t ld_tile(const unsigned short* t, int row, int kb) {
    int addr = (row * 128 + kb) ^ ((row & 7) << 4);
    union { uint4 u; short8t s; } cv;
    cv.u = *(const uint4*)((const char*)t + addr);
    return cv.s;
}
__device__ __forceinline__ void st_tile(unsigned short* t, int row, int kb, uint4 v) {
    int addr = (row * 128 + kb) ^ ((row & 7) << 4);
    *(uint4*)((char*)t + addr) = v;
}

// ---------------------------------------------------------------------------
// ROUND-20: KA rebalanced. R8 had KA_BLOCKS=391 on 256 CUs -> ~135 CUs ran
// TWO serialized KA blocks (crit = 2 x dur(2048)). Now 256 blocks x 3125
// edges (exact division): crit = 1 x dur(3125) ~ -25%. Plus R1->R2's proven
// phase-split: all 13 tgt/src pairs loaded unconditionally to REGISTERS (one
// latency, not 13 serialized load->atomic chains), hist from regs, packed
// pairs CARRIED IN REGS across the barriers -> epair LDS buffer deleted
// (-6250 LDS ops/block). k2 untouched (attribution).
// ---------------------------------------------------------------------------
__global__ __launch_bounds__(256) void k1_kernel(
        const float* __restrict__ data,
        const float* __restrict__ merge,
        const int* __restrict__ src, const int* __restrict__ tgt,
        const float* __restrict__ W_tr, const float* __restrict__ b_tr,
        unsigned short* __restrict__ data16,
        int* __restrict__ gCur, unsigned int* __restrict__ gPairs,
        float* __restrict__ outv) {
    __shared__ int hist[KBINS], rbase[KBINS], cur2[KBINS];          // 9.4 KB
    __shared__ __align__(16) unsigned short mtile[64 * 64];         // 8 KB
    int b = blockIdx.x;
    int tid = threadIdx.x;
    if (b < KA_BLOCKS) {
        int eb = b * KA_EDGES;           // n == KA_EDGES always (exact div)
        for (int i = tid; i < KBINS; i += 256) { hist[i] = 0; cur2[i] = 0; }
        // ---- phase A: all loads issued unconditionally (clamped) ----------
        int tg[KA_ITERS], sr[KA_ITERS];
#pragma unroll
        for (int j = 0; j < KA_ITERS; j++) {
            int i = j * 256 + tid;
            int ic = i < KA_EDGES ? i : 0;
            tg[j] = tgt[eb + ic];
            sr[j] = src[eb + ic];
        }
        __syncthreads();                 // hist zero visible
        // ---- phase B: register-only hist pass -----------------------------
        unsigned int pe[KA_ITERS];
#pragma unroll
        for (int j = 0; j < KA_ITERS; j++) {
            int i = j * 256 + tid;
            pe[j] = ((unsigned int)tg[j] << 16) | (unsigned int)sr[j];
            if (i < KA_EDGES) atomicAdd(&hist[tg[j] >> 6], 1);
        }
        __syncthreads();
        // ---- reserve runs in gPairs --------------------------------------
        for (int i = tid; i < KBINS; i += 256)
            if (hist[i] > 0)
                rbase[i] = atomicAdd(&gCur[i], hist[i]);
        __syncthreads();
        // ---- phase C: scatter from registers ------------------------------
#pragma unroll
        for (int j = 0; j < KA_ITERS; j++) {
            int i = j * 256 + tid;
            if (i < KA_EDGES) {
                unsigned int p = pe[j];
                int c = p >> 22;                        // tgt>>6
                int pos = rbase[c] + atomicAdd(&cur2[c], 1);
                if (pos < CCAP64) gPairs[(size_t)c * CCAP64 + pos] = p;
            }
        }
    } else if (b < KA_BLOCKS + GEMV_BLOCKS) {
        // ---- skip GEMM: out[64 rows] = merge@W_tr^T + b_tr (MFMA) ---------
        int gb = b - KA_BLOCKS;
        int lane = tid & 63;
        int w = tid >> 6;
        int rowBase = gb * 64;

        // stage merge tile -> bf16 LDS (swizzled): thread (r=tid>>2, q=tid&3)
        {
            int r = tid >> 2, q = tid & 3;
            int gr = rowBase + r; if (gr >= N_NODES) gr = N_NODES - 1;
            const float4* mp = (const float4*)(merge + (size_t)gr * D + q * 16);
            float4 f0 = mp[0], f1 = mp[1], f2 = mp[2], f3 = mp[3];
            union { short8t s; uint4 u; } c0, c1;
            c0.s = pack8(f0, f1); c1.s = pack8(f2, f3);
            st_tile(mtile, r, q * 32, c0.u);
            st_tile(mtile, r, q * 32 + 16, c1.u);
        }
        // B-frags: W_tr rows 16t+(lane&15), k floats (lane>>4)*8 + s*32
        short8t bfr[4][2];
        float bias[4];
#pragma unroll
        for (int t = 0; t < 4; t++) {
            int wrow = 16 * t + (lane & 15);
            bias[t] = b_tr[wrow];
#pragma unroll
            for (int s = 0; s < 2; s++) {
                const float4* wp = (const float4*)(W_tr + (size_t)wrow * D
                                                   + (lane >> 4) * 8 + s * 32);
                bfr[t][s] = pack8(wp[0], wp[1]);
            }
        }
        __syncthreads();

        f32x4 acc[4] = {{0,0,0,0},{0,0,0,0},{0,0,0,0},{0,0,0,0}};
#pragma unroll
        for (int s = 0; s < 2; s++) {
            short8t a = ld_tile(mtile, 16 * w + (lane & 15),
                                (lane >> 4) * 16 + s * 64);
#pragma unroll
            for (int t = 0; t < 4; t++)
                acc[t] = __builtin_amdgcn_mfma_f32_16x16x32_bf16(
                    a, bfr[t][s], acc[t], 0, 0, 0);
        }
        // C/D: row=(lane>>4)*4+j (node within strip), col=lane&15
#pragma unroll
        for (int t = 0; t < 4; t++) {
            int cl = 16 * t + (lane & 15);
#pragma unroll
            for (int j = 0; j < 4; j++) {
                int node = rowBase + 16 * w + (lane >> 4) * 4 + j;
                if (node < N_NODES)
                    outv[(size_t)node * D + cl] = acc[t][j] + bias[t];
            }
        }
    } else {
        int i = (b - KA_BLOCKS - GEMV_BLOCKS) * 256 + tid;   // float4 index
        float4 d = ((const float4*)data)[i];
        uint2 v;
        v.x = f2bf(d.x) | (f2bf(d.y) << 16);
        v.y = f2bf(d.z) | (f2bf(d.w) << 16);
        ((uint2*)data16)[i] = v;
    }
}

// ---------------------------------------------------------------------------
// K2: one block per 64-node bin. Scan (no filter) -> LDS buckets -> gather
// (branchless windows) -> h rows packed bf16 into swizzled tile -> MFMA
// epilogue: out = relu(h@W_lin^T + out_skip). UNCHANGED from R8.
// ---------------------------------------------------------------------------
__global__ __launch_bounds__(256) void k2_kernel(
        const float* __restrict__ data,
        const unsigned short* __restrict__ data16,
        const int* __restrict__ gCur,
        const unsigned int* __restrict__ gPairs,
        const float* __restrict__ W_lin,
        float* __restrict__ out) {
    __shared__ __align__(16) unsigned short lbkt[BIN_NODES * BROW];  // 9 KB
    __shared__ int lcur[BIN_NODES];
    __shared__ __align__(16) unsigned short hb[BIN_NODES * D];       // 8 KB bf16

    int tid = threadIdx.x;
    int lane = tid & 63;
    int bin = blockIdx.x;
    int nodeBase = bin * BIN_NODES;

    if (tid < BIN_NODES) lcur[tid] = 0;
    __syncthreads();

    // ---- scan: own bin, unconditional clamped loads, no filter ------------
    int cnt = gCur[bin]; if (cnt > CCAP64) cnt = CCAP64;
    const unsigned int* cp = gPairs + (size_t)bin * CCAP64;
    unsigned int pw[SCAN_W];
#pragma unroll
    for (int j = 0; j < SCAN_W; j++) {
        int i = j * 256 + tid;
        pw[j] = cp[i < cnt ? i : 0];
    }
#pragma unroll
    for (int j = 0; j < SCAN_W; j++) {
        int i = j * 256 + tid;
        unsigned int pr = pw[j];
        if (i < cnt) {
            int nd = (pr >> 16) & 63;            // local node within bin
            int pos = atomicAdd(&lcur[nd], 1);
            if (pos < NODE_CAP)
                lbkt[nd * BROW + pos] = (unsigned short)(pr & 0xffffu);
        }
    }
    __syncthreads();

    // ---- gather: group g=tid>>3 (0..31), lane ln=tid&7, par=g&1 -----------
    int g = tid >> 3;
    int ln = tid & 7;
    int par = g & 1;
    int nsel = g >> 1;                           // 0..15

#pragma unroll 1
    for (int q = 0; q < 4; q++) {
        int node = q * 16 + nsel;                // 0..63
        int n = nodeBase + node;
        int valid = n < N_NODES;
        int dg = lcur[node];
        int dgc = dg < NODE_CAP ? dg : NODE_CAP;

        const float4* orow = (const float4*)(data + (size_t)(valid ? n : 0) * D + 8 * ln);
        float4 o0 = orow[0], o1 = orow[1];

        const uint2* idxp = (const uint2*)(lbkt + node * BROW + par * 4);
        uint2 iw0 = idxp[0], iw1 = idxp[2], iw2 = idxp[4], iw3 = idxp[6];

        float af[4][8];
#pragma unroll
        for (int ch = 0; ch < 4; ch++)
#pragma unroll
            for (int k = 0; k < 8; k++) af[ch][k] = 0.f;

        {   // fast window: edges 0..15 -- branchless
            unsigned int idx[8]; float m[8];
            unsigned int iww[4] = { iw0.x, iw0.y, iw1.x, iw1.y };
#pragma unroll
            for (int qq = 0; qq < 4; qq++) {
                int e = (qq >> 1) * 8 + par * 4 + (qq & 1) * 2;
                unsigned int lo = iww[qq] & 0xffffu, hi = iww[qq] >> 16;
                idx[qq * 2]     = e     < dgc ? lo : 0u;
                m[qq * 2]       = e     < dgc ? 1.f : 0.f;
                idx[qq * 2 + 1] = e + 1 < dgc ? hi : 0u;
                m[qq * 2 + 1]   = e + 1 < dgc ? 1.f : 0.f;
            }
            uint4 v[8];
#pragma unroll
            for (int k = 0; k < 8; k++)
                v[k] = *(const uint4*)(data16 + (size_t)idx[k] * D + 8 * ln);
#pragma unroll
            for (int k = 0; k < 8; k++) {
                int ch = k & 3;
                af[ch][0] += m[k] * bflo(v[k].x); af[ch][1] += m[k] * bfhi(v[k].x);
                af[ch][2] += m[k] * bflo(v[k].y); af[ch][3] += m[k] * bfhi(v[k].y);
                af[ch][4] += m[k] * bflo(v[k].z); af[ch][5] += m[k] * bfhi(v[k].z);
                af[ch][6] += m[k] * bflo(v[k].w); af[ch][7] += m[k] * bfhi(v[k].w);
            }
        }
        // its 2..3: coarse group-uniform guard, branchless inside
#pragma unroll
        for (int it = 2; it < 4; it++) {
            int e0 = it * 8 + par * 4;
            if (e0 < dgc) {
                uint2 iw = (it == 2) ? iw2 : iw3;
                unsigned int i0 = iw.x & 0xffffu, i1 = iw.x >> 16;
                unsigned int i2 = iw.y & 0xffffu, i3 = iw.y >> 16;
                unsigned int jdx[4]; float mm[4];
                jdx[0] = i0;                       mm[0] = 1.f;
                jdx[1] = e0 + 1 < dgc ? i1 : 0u;   mm[1] = e0 + 1 < dgc ? 1.f : 0.f;
                jdx[2] = e0 + 2 < dgc ? i2 : 0u;   mm[2] = e0 + 2 < dgc ? 1.f : 0.f;
                jdx[3] = e0 + 3 < dgc ? i3 : 0u;   mm[3] = e0 + 3 < dgc ? 1.f : 0.f;
                uint4 vv[4];
#pragma unroll
                for (int k = 0; k < 4; k++)
                    vv[k] = *(const uint4*)(data16 + (size_t)jdx[k] * D + 8 * ln);
#pragma unroll
                for (int k = 0; k < 4; k++) {
                    af[k][0] += mm[k] * bflo(vv[k].x); af[k][1] += mm[k] * bfhi(vv[k].x);
                    af[k][2] += mm[k] * bflo(vv[k].y); af[k][3] += mm[k] * bfhi(vv[k].y);
                    af[k][4] += mm[k] * bflo(vv[k].z); af[k][5] += mm[k] * bfhi(vv[k].z);
                    af[k][6] += mm[k] * bflo(vv[k].w); af[k][7] += mm[k] * bfhi(vv[k].w);
                }
            }
        }
        // dynamic tail: deg > 32 (~6 nodes in the whole graph)
        int nIt = (dgc + 7) >> 3;
        for (int it = 4; it < nIt; it++) {
            uint2 iw = idxp[it * 2];
            int e0 = it * 8 + par * 4;
            unsigned int i0 = iw.x & 0xffffu, i1 = iw.x >> 16;
            unsigned int i2 = iw.y & 0xffffu, i3 = iw.y >> 16;
            unsigned int jdx[4]; float mm[4];
            jdx[0] = e0     < dgc ? i0 : 0u;   mm[0] = e0     < dgc ? 1.f : 0.f;
            jdx[1] = e0 + 1 < dgc ? i1 : 0u;   mm[1] = e0 + 1 < dgc ? 1.f : 0.f;
            jdx[2] = e0 + 2 < dgc ? i2 : 0u;   mm[2] = e0 + 2 < dgc ? 1.f : 0.f;
            jdx[3] = e0 + 3 < dgc ? i3 : 0u;   mm[3] = e0 + 3 < dgc ? 1.f : 0.f;
            uint4 vv[4];
#pragma unroll
            for (int k = 0; k < 4; k++)
                vv[k] = *(const uint4*)(data16 + (size_t)jdx[k] * D + 8 * ln);
#pragma unroll
            for (int k = 0; k < 4; k++) {
                af[k][0] += mm[k] * bflo(vv[k].x); af[k][1] += mm[k] * bfhi(vv[k].x);
                af[k][2] += mm[k] * bflo(vv[k].y); af[k][3] += mm[k] * bfhi(vv[k].y);
                af[k][4] += mm[k] * bflo(vv[k].z); af[k][5] += mm[k] * bfhi(vv[k].z);
                af[k][6] += mm[k] * bflo(vv[k].w); af[k][7] += mm[k] * bfhi(vv[k].w);
            }
        }

        float sv[8];
#pragma unroll
        for (int k = 0; k < 8; k++)
            sv[k] = (af[0][k] + af[1][k]) + (af[2][k] + af[3][k]);
#pragma unroll
        for (int k = 0; k < 8; k++) sv[k] += __shfl_xor(sv[k], 8);   // parities

        if (par == 0) {
            float inv = dg > 0 ? 1.0f / (float)dg : 0.0f;
            float msk = dg > 0 ? 1.0f : 0.0f;
            float4 h0, h1;
            h0.x = (o0.x - sv[0] * inv) * msk; h0.y = (o0.y - sv[1] * inv) * msk;
            h0.z = (o0.z - sv[2] * inv) * msk; h0.w = (o0.w - sv[3] * inv) * msk;
            h1.x = (o1.x - sv[4] * inv) * msk; h1.y = (o1.y - sv[5] * inv) * msk;
            h1.z = (o1.z - sv[6] * inv) * msk; h1.w = (o1.w - sv[7] * inv) * msk;
            // h row -> bf16 tile, cols 8ln..8ln+7 (16-byte block ln), swizzled
            union { short8t s; uint4 u; } hv;
            hv.s = pack8(h0, h1);
            st_tile(hb, node, ln * 16, hv.u);
        }
    }

    // ---- MFMA epilogue operand prefetch (latency hidden under barrier) ----
    int w = tid >> 6;
    short8t bfr[4][2];
#pragma unroll
    for (int t = 0; t < 4; t++)
#pragma unroll
        for (int s = 0; s < 2; s++) {
            const float4* wp = (const float4*)(W_lin
                + (size_t)(16 * t + (lane & 15)) * D + (lane >> 4) * 8 + s * 32);
            bfr[t][s] = pack8(wp[0], wp[1]);
        }
    float oldv[4][4];
#pragma unroll
    for (int t = 0; t < 4; t++) {
        int cl = 16 * t + (lane & 15);
#pragma unroll
        for (int j = 0; j < 4; j++) {
            int node = nodeBase + 16 * w + (lane >> 4) * 4 + j;
            oldv[t][j] = out[(size_t)(node < N_NODES ? node : 0) * D + cl];
        }
    }
    __syncthreads();

    // ---- MFMA: wave w -> rows 16w..16w+15; out = relu(h@W_lin^T + skip) ---
    f32x4 acc[4] = {{0,0,0,0},{0,0,0,0},{0,0,0,0},{0,0,0,0}};
#pragma unroll
    for (int s = 0; s < 2; s++) {
        short8t a = ld_tile(hb, 16 * w + (lane & 15), (lane >> 4) * 16 + s * 64);
#pragma unroll
        for (int t = 0; t < 4; t++)
            acc[t] = __builtin_amdgcn_mfma_f32_16x16x32_bf16(
                a, bfr[t][s], acc[t], 0, 0, 0);
    }
#pragma unroll
    for (int t = 0; t < 4; t++) {
        int cl = 16 * t + (lane & 15);
#pragma unroll
        for (int j = 0; j < 4; j++) {
            int node = nodeBase + 16 * w + (lane >> 4) * 4 + j;
            if (node < N_NODES) {
                float o = acc[t][j] + oldv[t][j];
                out[(size_t)node * D + cl] = o > 0.f ? o : 0.f;
            }
        }
    }
}

extern "C" void kernel_launch(void* const* d_in, const int* in_sizes, int n_in,
                              void* d_out, int out_size, void* d_ws, size_t ws_size,
                              hipStream_t stream) {
    const float* data  = (const float*)d_in[0];
    const float* merge = (const float*)d_in[1];
    const int*   src   = (const int*)d_in[2];
    const int*   tgt   = (const int*)d_in[3];
    // d_in[4]=W_lin, d_in[5]=b_lin (cancels in lap), d_in[6]=W_tr, d_in[7]=b_tr
    const float* W_lin = (const float*)d_in[4];
    const float* W_tr  = (const float*)d_in[6];
    const float* b_tr  = (const float*)d_in[7];
    float* out = (float*)d_out;

    // Workspace: gCur[1024 i32] | gPairs[782*1280 u32] (4.0 MB)
    //            | data16[N*D bf16] (6.4 MB)            total ~10.4 MB
    char* ws = (char*)d_ws;
    size_t o = 0;
    int*            gCur   = (int*)(ws + o);            o += 1024 * 4;
    unsigned int*   gPairs = (unsigned int*)(ws + o);   o += (size_t)KBINS * CCAP64 * 4;
    unsigned short* data16 = (unsigned short*)(ws + o); o += (size_t)N_NODES * D * 2;

    hipMemsetAsync(gCur, 0, KBINS * 4, stream);

    k1_kernel<<<K1_BLOCKS, 256, 0, stream>>>(
        data, merge, src, tgt, W_tr, b_tr, data16, gCur, gPairs, out);

    k2_kernel<<<KBINS, 256, 0, stream>>>(
        data, data16, gCur, gPairs, W_lin, out);
}

// Round 10
// 133.851 us; speedup vs baseline: 3.1134x; 1.0154x over previous
//
#include <hip/hip_runtime.h>

#define N_NODES 50000
#define N_EDGES 800000
#define D 64
#define KBINS 782            // 64-node bins (tgt>>6); 782*64 = 50048 >= N
#define CCAP64 1280          // edges/bin: mean 1024, sigma 32 -> +8 sigma
#define BIN_NODES 64         // k2 nodes per block
#define NODE_CAP 64          // deg ~ Poisson(16); P(>64) ~ 1e-18
#define BROW 72              // u16 stride per node bucket in LDS (144 B)
#define KA_BLOCKS 256        // ONE KA block per CU (800000/256 = 3125 exact)
#define KA_EDGES 3125
#define KA_ITERS 13          // ceil(3125/256)
#define GEMV_BLOCKS 782      // 64 rows per block (merge@W_tr^T via MFMA)
#define CVT_BLOCKS 3125
#define K1_BLOCKS (KA_BLOCKS + GEMV_BLOCKS + CVT_BLOCKS)
#define SCAN_W 5             // ceil(CCAP64/256) scan words per thread
#define MAGIC 0x7A3F19E5u    // flag value; not byte-replicated (poison-safe)

typedef __attribute__((ext_vector_type(8))) short short8t;   // 8 bf16 (4 VGPR)
typedef __attribute__((ext_vector_type(4))) float f32x4;     // MFMA acc

__device__ __forceinline__ unsigned int f2bf(float f) {
    unsigned int u = __builtin_bit_cast(unsigned int, f);
    return (u + 0x7fffu + ((u >> 16) & 1u)) >> 16;
}
__device__ __forceinline__ float bflo(unsigned int v) {
    return __builtin_bit_cast(float, v << 16);
}
__device__ __forceinline__ float bfhi(unsigned int v) {
    return __builtin_bit_cast(float, v & 0xffff0000u);
}
__device__ __forceinline__ short8t pack8(float4 a, float4 b) {
    union { uint4 u; short8t s; } cv;
    cv.u.x = f2bf(a.x) | (f2bf(a.y) << 16);
    cv.u.y = f2bf(a.z) | (f2bf(a.w) << 16);
    cv.u.z = f2bf(b.x) | (f2bf(b.y) << 16);
    cv.u.w = f2bf(b.z) | (f2bf(b.w) << 16);
    return cv.s;
}
// LDS bf16 tile [64 rows][64 cols] (128 B/row) with XOR swizzle (G4).
__device__ __forceinline__ short8t ld_tile(const unsigned short* t, int row, int kb) {
    int addr = (row * 128 + kb) ^ ((row & 7) << 4);
    union { uint4 u; short8t s; } cv;
    cv.u = *(const uint4*)((const char*)t + addr);
    return cv.s;
}
__device__ __forceinline__ void st_tile(unsigned short* t, int row, int kb, uint4 v) {
    int addr = (row * 128 + kb) ^ ((row & 7) << 4);
    *(uint4*)((char*)t + addr) = v;
}

// ---------------------------------------------------------------------------
// ROUND-21:
// (1) memset dispatch FOLDED into k1: block 0 zeroes gCur via atomicExch
//     (coherence point -- R3 lesson), __threadfence, publishes MAGIC flag at
//     gCur[1023]; KA blocks atomic-spin on the flag only right before their
//     reserve atomicAdd (~3 us of load/hist work already done -> spin ~never
//     taken). All 256 KA blocks co-resident on 256 CUs -> no deadlock.
// (2) k2 gather fully branchless over 16 edge slots: all 16 uint4 loads
//     issue back-to-back (one global latency per task, was two -- the
//     guarded batch-2 blocked load hoisting, same mechanism as R1's fix).
// ---------------------------------------------------------------------------
__global__ __launch_bounds__(256) void k1_kernel(
        const float* __restrict__ data,
        const float* __restrict__ merge,
        const int* __restrict__ src, const int* __restrict__ tgt,
        const float* __restrict__ W_tr, const float* __restrict__ b_tr,
        unsigned short* __restrict__ data16,
        int* __restrict__ gCur, unsigned int* __restrict__ gPairs,
        float* __restrict__ outv) {
    __shared__ int hist[KBINS], rbase[KBINS], cur2[KBINS];          // 9.4 KB
    __shared__ __align__(16) unsigned short mtile[64 * 64];         // 8 KB
    int b = blockIdx.x;
    int tid = threadIdx.x;
    if (b < KA_BLOCKS) {
        int eb = b * KA_EDGES;           // n == KA_EDGES always (exact div)
        // block 0: zero gCur at the coherence point, then publish flag
        if (b == 0) {
            for (int i = tid; i < KBINS; i += 256) atomicExch(&gCur[i], 0);
            __threadfence();
            __syncthreads();
            if (tid == 0)
                atomicExch((unsigned int*)&gCur[1023], MAGIC);
        }
        for (int i = tid; i < KBINS; i += 256) { hist[i] = 0; cur2[i] = 0; }
        // ---- phase A: all loads issued unconditionally (clamped) ----------
        int tg[KA_ITERS], sr[KA_ITERS];
#pragma unroll
        for (int j = 0; j < KA_ITERS; j++) {
            int i = j * 256 + tid;
            int ic = i < KA_EDGES ? i : 0;
            tg[j] = tgt[eb + ic];
            sr[j] = src[eb + ic];
        }
        __syncthreads();                 // hist zero visible
        // ---- phase B: register-only hist pass -----------------------------
        unsigned int pe[KA_ITERS];
#pragma unroll
        for (int j = 0; j < KA_ITERS; j++) {
            int i = j * 256 + tid;
            pe[j] = ((unsigned int)tg[j] << 16) | (unsigned int)sr[j];
            if (i < KA_EDGES) atomicAdd(&hist[tg[j] >> 6], 1);
        }
        __syncthreads();
        // ---- wait for gCur zeroing (flag), then reserve runs --------------
        if (tid == 0) {
            while (atomicAdd((unsigned int*)&gCur[1023], 0u) != MAGIC) {}
        }
        __syncthreads();
        for (int i = tid; i < KBINS; i += 256)
            if (hist[i] > 0)
                rbase[i] = atomicAdd(&gCur[i], hist[i]);
        __syncthreads();
        // ---- phase C: scatter from registers ------------------------------
#pragma unroll
        for (int j = 0; j < KA_ITERS; j++) {
            int i = j * 256 + tid;
            if (i < KA_EDGES) {
                unsigned int p = pe[j];
                int c = p >> 22;                        // tgt>>6
                int pos = rbase[c] + atomicAdd(&cur2[c], 1);
                if (pos < CCAP64) gPairs[(size_t)c * CCAP64 + pos] = p;
            }
        }
    } else if (b < KA_BLOCKS + GEMV_BLOCKS) {
        // ---- skip GEMM: out[64 rows] = merge@W_tr^T + b_tr (MFMA) ---------
        int gb = b - KA_BLOCKS;
        int lane = tid & 63;
        int w = tid >> 6;
        int rowBase = gb * 64;

        // stage merge tile -> bf16 LDS (swizzled): thread (r=tid>>2, q=tid&3)
        {
            int r = tid >> 2, q = tid & 3;
            int gr = rowBase + r; if (gr >= N_NODES) gr = N_NODES - 1;
            const float4* mp = (const float4*)(merge + (size_t)gr * D + q * 16);
            float4 f0 = mp[0], f1 = mp[1], f2 = mp[2], f3 = mp[3];
            union { short8t s; uint4 u; } c0, c1;
            c0.s = pack8(f0, f1); c1.s = pack8(f2, f3);
            st_tile(mtile, r, q * 32, c0.u);
            st_tile(mtile, r, q * 32 + 16, c1.u);
        }
        // B-frags: W_tr rows 16t+(lane&15), k floats (lane>>4)*8 + s*32
        short8t bfr[4][2];
        float bias[4];
#pragma unroll
        for (int t = 0; t < 4; t++) {
            int wrow = 16 * t + (lane & 15);
            bias[t] = b_tr[wrow];
#pragma unroll
            for (int s = 0; s < 2; s++) {
                const float4* wp = (const float4*)(W_tr + (size_t)wrow * D
                                                   + (lane >> 4) * 8 + s * 32);
                bfr[t][s] = pack8(wp[0], wp[1]);
            }
        }
        __syncthreads();

        f32x4 acc[4] = {{0,0,0,0},{0,0,0,0},{0,0,0,0},{0,0,0,0}};
#pragma unroll
        for (int s = 0; s < 2; s++) {
            short8t a = ld_tile(mtile, 16 * w + (lane & 15),
                                (lane >> 4) * 16 + s * 64);
#pragma unroll
            for (int t = 0; t < 4; t++)
                acc[t] = __builtin_amdgcn_mfma_f32_16x16x32_bf16(
                    a, bfr[t][s], acc[t], 0, 0, 0);
        }
        // C/D: row=(lane>>4)*4+j (node within strip), col=lane&15
#pragma unroll
        for (int t = 0; t < 4; t++) {
            int cl = 16 * t + (lane & 15);
#pragma unroll
            for (int j = 0; j < 4; j++) {
                int node = rowBase + 16 * w + (lane >> 4) * 4 + j;
                if (node < N_NODES)
                    outv[(size_t)node * D + cl] = acc[t][j] + bias[t];
            }
        }
    } else {
        int i = (b - KA_BLOCKS - GEMV_BLOCKS) * 256 + tid;   // float4 index
        float4 d = ((const float4*)data)[i];
        uint2 v;
        v.x = f2bf(d.x) | (f2bf(d.y) << 16);
        v.y = f2bf(d.z) | (f2bf(d.w) << 16);
        ((uint2*)data16)[i] = v;
    }
}

// ---------------------------------------------------------------------------
// K2: one block per 64-node bin. Scan (no filter) -> LDS buckets -> gather
// (BRANCHLESS 16-slot batch: one global latency per task) -> h rows packed
// bf16 into swizzled tile -> MFMA epilogue: out = relu(h@W_lin^T + skip).
// ---------------------------------------------------------------------------
__global__ __launch_bounds__(256) void k2_kernel(
        const float* __restrict__ data,
        const unsigned short* __restrict__ data16,
        const int* __restrict__ gCur,
        const unsigned int* __restrict__ gPairs,
        const float* __restrict__ W_lin,
        float* __restrict__ out) {
    __shared__ __align__(16) unsigned short lbkt[BIN_NODES * BROW];  // 9 KB
    __shared__ int lcur[BIN_NODES];
    __shared__ __align__(16) unsigned short hb[BIN_NODES * D];       // 8 KB bf16

    int tid = threadIdx.x;
    int lane = tid & 63;
    int bin = blockIdx.x;
    int nodeBase = bin * BIN_NODES;

    if (tid < BIN_NODES) lcur[tid] = 0;
    __syncthreads();

    // ---- scan: own bin, unconditional clamped loads, no filter ------------
    int cnt = gCur[bin]; if (cnt > CCAP64) cnt = CCAP64;
    const unsigned int* cp = gPairs + (size_t)bin * CCAP64;
    unsigned int pw[SCAN_W];
#pragma unroll
    for (int j = 0; j < SCAN_W; j++) {
        int i = j * 256 + tid;
        pw[j] = cp[i < cnt ? i : 0];
    }
#pragma unroll
    for (int j = 0; j < SCAN_W; j++) {
        int i = j * 256 + tid;
        unsigned int pr = pw[j];
        if (i < cnt) {
            int nd = (pr >> 16) & 63;            // local node within bin
            int pos = atomicAdd(&lcur[nd], 1);
            if (pos < NODE_CAP)
                lbkt[nd * BROW + pos] = (unsigned short)(pr & 0xffffu);
        }
    }
    __syncthreads();

    // ---- gather: group g=tid>>3 (0..31), lane ln=tid&7, par=g&1 -----------
    int g = tid >> 3;
    int ln = tid & 7;
    int par = g & 1;
    int nsel = g >> 1;                           // 0..15

#pragma unroll 1
    for (int q = 0; q < 4; q++) {
        int node = q * 16 + nsel;                // 0..63
        int n = nodeBase + node;
        int valid = n < N_NODES;
        int dg = lcur[node];
        int dgc = dg < NODE_CAP ? dg : NODE_CAP;

        const float4* orow = (const float4*)(data + (size_t)(valid ? n : 0) * D + 8 * ln);
        float4 o0 = orow[0], o1 = orow[1];

        const uint2* idxp = (const uint2*)(lbkt + node * BROW + par * 4);
        uint2 iw0 = idxp[0], iw1 = idxp[2], iw2 = idxp[4], iw3 = idxp[6];

        float af[4][8];
#pragma unroll
        for (int ch = 0; ch < 4; ch++)
#pragma unroll
            for (int k = 0; k < 8; k++) af[ch][k] = 0.f;

        // ---- branchless 16-slot batch: edges it*8+par*4+{0..3}, it=0..3 ---
        // All 16 loads issue back-to-back (no guards in front of any load).
        {
            unsigned int idx[16]; float m[16];
            unsigned int iww[8] = { iw0.x, iw0.y, iw1.x, iw1.y,
                                    iw2.x, iw2.y, iw3.x, iw3.y };
#pragma unroll
            for (int qq = 0; qq < 8; qq++) {
                int e = (qq >> 1) * 8 + par * 4 + (qq & 1) * 2;
                unsigned int lo = iww[qq] & 0xffffu, hi = iww[qq] >> 16;
                idx[qq * 2]     = e     < dgc ? lo : 0u;
                m[qq * 2]       = e     < dgc ? 1.f : 0.f;
                idx[qq * 2 + 1] = e + 1 < dgc ? hi : 0u;
                m[qq * 2 + 1]   = e + 1 < dgc ? 1.f : 0.f;
            }
            uint4 v[16];
#pragma unroll
            for (int k = 0; k < 16; k++)
                v[k] = *(const uint4*)(data16 + (size_t)idx[k] * D + 8 * ln);
#pragma unroll
            for (int k = 0; k < 16; k++) {
                int ch = k & 3;
                af[ch][0] += m[k] * bflo(v[k].x); af[ch][1] += m[k] * bfhi(v[k].x);
                af[ch][2] += m[k] * bflo(v[k].y); af[ch][3] += m[k] * bfhi(v[k].y);
                af[ch][4] += m[k] * bflo(v[k].z); af[ch][5] += m[k] * bfhi(v[k].z);
                af[ch][6] += m[k] * bflo(v[k].w); af[ch][7] += m[k] * bfhi(v[k].w);
            }
        }
        // dynamic tail: deg > 32 (~6 nodes in the whole graph)
        int nIt = (dgc + 7) >> 3;
        for (int it = 4; it < nIt; it++) {
            uint2 iw = idxp[it * 2];
            int e0 = it * 8 + par * 4;
            unsigned int i0 = iw.x & 0xffffu, i1 = iw.x >> 16;
            unsigned int i2 = iw.y & 0xffffu, i3 = iw.y >> 16;
            unsigned int jdx[4]; float mm[4];
            jdx[0] = e0     < dgc ? i0 : 0u;   mm[0] = e0     < dgc ? 1.f : 0.f;
            jdx[1] = e0 + 1 < dgc ? i1 : 0u;   mm[1] = e0 + 1 < dgc ? 1.f : 0.f;
            jdx[2] = e0 + 2 < dgc ? i2 : 0u;   mm[2] = e0 + 2 < dgc ? 1.f : 0.f;
            jdx[3] = e0 + 3 < dgc ? i3 : 0u;   mm[3] = e0 + 3 < dgc ? 1.f : 0.f;
            uint4 vv[4];
#pragma unroll
            for (int k = 0; k < 4; k++)
                vv[k] = *(const uint4*)(data16 + (size_t)jdx[k] * D + 8 * ln);
#pragma unroll
            for (int k = 0; k < 4; k++) {
                af[k][0] += mm[k] * bflo(vv[k].x); af[k][1] += mm[k] * bfhi(vv[k].x);
                af[k][2] += mm[k] * bflo(vv[k].y); af[k][3] += mm[k] * bfhi(vv[k].y);
                af[k][4] += mm[k] * bflo(vv[k].z); af[k][5] += mm[k] * bfhi(vv[k].z);
                af[k][6] += mm[k] * bflo(vv[k].w); af[k][7] += mm[k] * bfhi(vv[k].w);
            }
        }

        float sv[8];
#pragma unroll
        for (int k = 0; k < 8; k++)
            sv[k] = (af[0][k] + af[1][k]) + (af[2][k] + af[3][k]);
#pragma unroll
        for (int k = 0; k < 8; k++) sv[k] += __shfl_xor(sv[k], 8);   // parities

        if (par == 0) {
            float inv = dg > 0 ? 1.0f / (float)dg : 0.0f;
            float msk = dg > 0 ? 1.0f : 0.0f;
            float4 h0, h1;
            h0.x = (o0.x - sv[0] * inv) * msk; h0.y = (o0.y - sv[1] * inv) * msk;
            h0.z = (o0.z - sv[2] * inv) * msk; h0.w = (o0.w - sv[3] * inv) * msk;
            h1.x = (o1.x - sv[4] * inv) * msk; h1.y = (o1.y - sv[5] * inv) * msk;
            h1.z = (o1.z - sv[6] * inv) * msk; h1.w = (o1.w - sv[7] * inv) * msk;
            // h row -> bf16 tile, cols 8ln..8ln+7 (16-byte block ln), swizzled
            union { short8t s; uint4 u; } hv;
            hv.s = pack8(h0, h1);
            st_tile(hb, node, ln * 16, hv.u);
        }
    }

    // ---- MFMA epilogue operand prefetch (latency hidden under barrier) ----
    int w = tid >> 6;
    short8t bfr[4][2];
#pragma unroll
    for (int t = 0; t < 4; t++)
#pragma unroll
        for (int s = 0; s < 2; s++) {
            const float4* wp = (const float4*)(W_lin
                + (size_t)(16 * t + (lane & 15)) * D + (lane >> 4) * 8 + s * 32);
            bfr[t][s] = pack8(wp[0], wp[1]);
        }
    float oldv[4][4];
#pragma unroll
    for (int t = 0; t < 4; t++) {
        int cl = 16 * t + (lane & 15);
#pragma unroll
        for (int j = 0; j < 4; j++) {
            int node = nodeBase + 16 * w + (lane >> 4) * 4 + j;
            oldv[t][j] = out[(size_t)(node < N_NODES ? node : 0) * D + cl];
        }
    }
    __syncthreads();

    // ---- MFMA: wave w -> rows 16w..16w+15; out = relu(h@W_lin^T + skip) ---
    f32x4 acc[4] = {{0,0,0,0},{0,0,0,0},{0,0,0,0},{0,0,0,0}};
#pragma unroll
    for (int s = 0; s < 2; s++) {
        short8t a = ld_tile(hb, 16 * w + (lane & 15), (lane >> 4) * 16 + s * 64);
#pragma unroll
        for (int t = 0; t < 4; t++)
            acc[t] = __builtin_amdgcn_mfma_f32_16x16x32_bf16(
                a, bfr[t][s], acc[t], 0, 0, 0);
    }
#pragma unroll
    for (int t = 0; t < 4; t++) {
        int cl = 16 * t + (lane & 15);
#pragma unroll
        for (int j = 0; j < 4; j++) {
            int node = nodeBase + 16 * w + (lane >> 4) * 4 + j;
            if (node < N_NODES) {
                float o = acc[t][j] + oldv[t][j];
                out[(size_t)node * D + cl] = o > 0.f ? o : 0.f;
            }
        }
    }
}

extern "C" void kernel_launch(void* const* d_in, const int* in_sizes, int n_in,
                              void* d_out, int out_size, void* d_ws, size_t ws_size,
                              hipStream_t stream) {
    const float* data  = (const float*)d_in[0];
    const float* merge = (const float*)d_in[1];
    const int*   src   = (const int*)d_in[2];
    const int*   tgt   = (const int*)d_in[3];
    // d_in[4]=W_lin, d_in[5]=b_lin (cancels in lap), d_in[6]=W_tr, d_in[7]=b_tr
    const float* W_lin = (const float*)d_in[4];
    const float* W_tr  = (const float*)d_in[6];
    const float* b_tr  = (const float*)d_in[7];
    float* out = (float*)d_out;

    // Workspace: gCur[1024 i32, flag at 1023] | gPairs[782*1280 u32] (4.0 MB)
    //            | data16[N*D bf16] (6.4 MB)            total ~10.4 MB
    char* ws = (char*)d_ws;
    size_t o = 0;
    int*            gCur   = (int*)(ws + o);            o += 1024 * 4;
    unsigned int*   gPairs = (unsigned int*)(ws + o);   o += (size_t)KBINS * CCAP64 * 4;
    unsigned short* data16 = (unsigned short*)(ws + o); o += (size_t)N_NODES * D * 2;

    // no memset: k1 block 0 zeroes gCur in-kernel (flag handshake)

    k1_kernel<<<K1_BLOCKS, 256, 0, stream>>>(
        data, merge, src, tgt, W_tr, b_tr, data16, gCur, gPairs, out);

    k2_kernel<<<KBINS, 256, 0, stream>>>(
        data, data16, gCur, gPairs, W_lin, out);
}

// Round 11
// 132.290 us; speedup vs baseline: 3.1502x; 1.0118x over previous
//
#include <hip/hip_runtime.h>

#define N_NODES 50000
#define N_EDGES 800000
#define D 64
#define KBINS 782            // 64-node bins (tgt>>6); 782*64 = 50048 >= N
#define CCAP64 1280          // edges/bin: mean 1024, sigma 32 -> +8 sigma
#define BIN_NODES 64         // k2 nodes per block
#define NODE_CAP 64          // deg ~ Poisson(16); P(>64) ~ 1e-18
#define BROW 72              // u16 stride per node bucket in LDS (144 B)
#define KA_BLOCKS 256        // ONE KA block per CU (800000/256 = 3125 exact)
#define KA_EDGES 3125
#define KA_ITERS 13          // ceil(3125/256)
#define GEMV_BLOCKS 782      // 64 rows per block (merge@W_tr^T via MFMA)
#define CVT_BLOCKS 3125
#define K1_BLOCKS (KA_BLOCKS + GEMV_BLOCKS + CVT_BLOCKS)
#define SCAN_W 5             // ceil(CCAP64/256) scan words per thread
#define MAGIC 0x7A3F19E5u    // flag value; not byte-replicated (poison-safe)
#define ZROW 50000u          // zero row in data16 (sentinel gather target)

typedef __attribute__((ext_vector_type(8))) short short8t;   // 8 bf16 (4 VGPR)
typedef __attribute__((ext_vector_type(4))) float f32x4;     // MFMA acc

__device__ __forceinline__ unsigned int f2bf(float f) {
    unsigned int u = __builtin_bit_cast(unsigned int, f);
    return (u + 0x7fffu + ((u >> 16) & 1u)) >> 16;
}
__device__ __forceinline__ float bflo(unsigned int v) {
    return __builtin_bit_cast(float, v << 16);
}
__device__ __forceinline__ float bfhi(unsigned int v) {
    return __builtin_bit_cast(float, v & 0xffff0000u);
}
__device__ __forceinline__ short8t pack8(float4 a, float4 b) {
    union { uint4 u; short8t s; } cv;
    cv.u.x = f2bf(a.x) | (f2bf(a.y) << 16);
    cv.u.y = f2bf(a.z) | (f2bf(a.w) << 16);
    cv.u.z = f2bf(b.x) | (f2bf(b.y) << 16);
    cv.u.w = f2bf(b.z) | (f2bf(b.w) << 16);
    return cv.s;
}
// LDS bf16 tile [64 rows][64 cols] (128 B/row) with XOR swizzle (G4).
__device__ __forceinline__ short8t ld_tile(const unsigned short* t, int row, int kb) {
    int addr = (row * 128 + kb) ^ ((row & 7) << 4);
    union { uint4 u; short8t s; } cv;
    cv.u = *(const uint4*)((const char*)t + addr);
    return cv.s;
}
__device__ __forceinline__ void st_tile(unsigned short* t, int row, int kb, uint4 v) {
    int addr = (row * 128 + kb) ^ ((row & 7) << 4);
    *(uint4*)((char*)t + addr) = v;
}

// ---------------------------------------------------------------------------
// ROUND-22: ZERO-ROW gather. R10 lesson: per-dispatch overhead is small and
// the 2nd load batch was already TLP-hidden; the remaining identified lump is
// gather VALU (~12-15 us device-wide: per-slot cmp/cndmask + mask-FMAs).
// Fix: data16 gets a zeroed row at index 50000; LDS buckets are PRE-FILLED
// with ZROW before the scan append, so every slot 0..63 holds a valid row
// index -- invalid slots fetch zeros and add 0.0. Deletes slot-validity
// cmp/cndmask, the m[] array, mask multiplies, and the dgc dependency in
// front of the loads. k1 unchanged except the one-time zero-row write.
// ---------------------------------------------------------------------------
__global__ __launch_bounds__(256) void k1_kernel(
        const float* __restrict__ data,
        const float* __restrict__ merge,
        const int* __restrict__ src, const int* __restrict__ tgt,
        const float* __restrict__ W_tr, const float* __restrict__ b_tr,
        unsigned short* __restrict__ data16,
        int* __restrict__ gCur, unsigned int* __restrict__ gPairs,
        float* __restrict__ outv) {
    __shared__ int hist[KBINS], rbase[KBINS], cur2[KBINS];          // 9.4 KB
    __shared__ __align__(16) unsigned short mtile[64 * 64];         // 8 KB
    int b = blockIdx.x;
    int tid = threadIdx.x;
    if (b < KA_BLOCKS) {
        int eb = b * KA_EDGES;           // n == KA_EDGES always (exact div)
        // block 0: zero gCur at the coherence point, then publish flag
        if (b == 0) {
            for (int i = tid; i < KBINS; i += 256) atomicExch(&gCur[i], 0);
            __threadfence();
            __syncthreads();
            if (tid == 0)
                atomicExch((unsigned int*)&gCur[1023], MAGIC);
        }
        for (int i = tid; i < KBINS; i += 256) { hist[i] = 0; cur2[i] = 0; }
        // ---- phase A: all loads issued unconditionally (clamped) ----------
        int tg[KA_ITERS], sr[KA_ITERS];
#pragma unroll
        for (int j = 0; j < KA_ITERS; j++) {
            int i = j * 256 + tid;
            int ic = i < KA_EDGES ? i : 0;
            tg[j] = tgt[eb + ic];
            sr[j] = src[eb + ic];
        }
        __syncthreads();                 // hist zero visible
        // ---- phase B: register-only hist pass -----------------------------
        unsigned int pe[KA_ITERS];
#pragma unroll
        for (int j = 0; j < KA_ITERS; j++) {
            int i = j * 256 + tid;
            pe[j] = ((unsigned int)tg[j] << 16) | (unsigned int)sr[j];
            if (i < KA_EDGES) atomicAdd(&hist[tg[j] >> 6], 1);
        }
        __syncthreads();
        // ---- wait for gCur zeroing (flag), then reserve runs --------------
        if (tid == 0) {
            while (atomicAdd((unsigned int*)&gCur[1023], 0u) != MAGIC) {}
        }
        __syncthreads();
        for (int i = tid; i < KBINS; i += 256)
            if (hist[i] > 0)
                rbase[i] = atomicAdd(&gCur[i], hist[i]);
        __syncthreads();
        // ---- phase C: scatter from registers ------------------------------
#pragma unroll
        for (int j = 0; j < KA_ITERS; j++) {
            int i = j * 256 + tid;
            if (i < KA_EDGES) {
                unsigned int p = pe[j];
                int c = p >> 22;                        // tgt>>6
                int pos = rbase[c] + atomicAdd(&cur2[c], 1);
                if (pos < CCAP64) gPairs[(size_t)c * CCAP64 + pos] = p;
            }
        }
    } else if (b < KA_BLOCKS + GEMV_BLOCKS) {
        // ---- skip GEMM: out[64 rows] = merge@W_tr^T + b_tr (MFMA) ---------
        int gb = b - KA_BLOCKS;
        int lane = tid & 63;
        int w = tid >> 6;
        int rowBase = gb * 64;

        // stage merge tile -> bf16 LDS (swizzled): thread (r=tid>>2, q=tid&3)
        {
            int r = tid >> 2, q = tid & 3;
            int gr = rowBase + r; if (gr >= N_NODES) gr = N_NODES - 1;
            const float4* mp = (const float4*)(merge + (size_t)gr * D + q * 16);
            float4 f0 = mp[0], f1 = mp[1], f2 = mp[2], f3 = mp[3];
            union { short8t s; uint4 u; } c0, c1;
            c0.s = pack8(f0, f1); c1.s = pack8(f2, f3);
            st_tile(mtile, r, q * 32, c0.u);
            st_tile(mtile, r, q * 32 + 16, c1.u);
        }
        // B-frags: W_tr rows 16t+(lane&15), k floats (lane>>4)*8 + s*32
        short8t bfr[4][2];
        float bias[4];
#pragma unroll
        for (int t = 0; t < 4; t++) {
            int wrow = 16 * t + (lane & 15);
            bias[t] = b_tr[wrow];
#pragma unroll
            for (int s = 0; s < 2; s++) {
                const float4* wp = (const float4*)(W_tr + (size_t)wrow * D
                                                   + (lane >> 4) * 8 + s * 32);
                bfr[t][s] = pack8(wp[0], wp[1]);
            }
        }
        __syncthreads();

        f32x4 acc[4] = {{0,0,0,0},{0,0,0,0},{0,0,0,0},{0,0,0,0}};
#pragma unroll
        for (int s = 0; s < 2; s++) {
            short8t a = ld_tile(mtile, 16 * w + (lane & 15),
                                (lane >> 4) * 16 + s * 64);
#pragma unroll
            for (int t = 0; t < 4; t++)
                acc[t] = __builtin_amdgcn_mfma_f32_16x16x32_bf16(
                    a, bfr[t][s], acc[t], 0, 0, 0);
        }
        // C/D: row=(lane>>4)*4+j (node within strip), col=lane&15
#pragma unroll
        for (int t = 0; t < 4; t++) {
            int cl = 16 * t + (lane & 15);
#pragma unroll
            for (int j = 0; j < 4; j++) {
                int node = rowBase + 16 * w + (lane >> 4) * 4 + j;
                if (node < N_NODES)
                    outv[(size_t)node * D + cl] = acc[t][j] + bias[t];
            }
        }
    } else {
        int i = (b - KA_BLOCKS - GEMV_BLOCKS) * 256 + tid;   // float4 index
        float4 d = ((const float4*)data)[i];
        uint2 v;
        v.x = f2bf(d.x) | (f2bf(d.y) << 16);
        v.y = f2bf(d.z) | (f2bf(d.w) << 16);
        ((uint2*)data16)[i] = v;
        // first CVT block also zeroes the sentinel row (index ZROW)
        if (b == KA_BLOCKS + GEMV_BLOCKS && tid < 16) {
            uint2 z; z.x = 0u; z.y = 0u;
            ((uint2*)(data16 + (size_t)ZROW * D))[tid] = z;
        }
    }
}

// ---------------------------------------------------------------------------
// K2: one block per 64-node bin. Buckets PRE-FILLED with ZROW -> scan append
// overwrites real indices -> gather is mask-free (pad slots add 0.0 from the
// zero row). MFMA epilogue: out = relu(h@W_lin^T + skip).
// ---------------------------------------------------------------------------
__global__ __launch_bounds__(256) void k2_kernel(
        const float* __restrict__ data,
        const unsigned short* __restrict__ data16,
        const int* __restrict__ gCur,
        const unsigned int* __restrict__ gPairs,
        const float* __restrict__ W_lin,
        float* __restrict__ out) {
    __shared__ __align__(16) unsigned short lbkt[BIN_NODES * BROW];  // 9 KB
    __shared__ int lcur[BIN_NODES];
    __shared__ __align__(16) unsigned short hb[BIN_NODES * D];       // 8 KB bf16

    int tid = threadIdx.x;
    int lane = tid & 63;
    int bin = blockIdx.x;
    int nodeBase = bin * BIN_NODES;

    // pre-fill bucket slots 0..63 of every node with ZROW (sentinel).
    // chunk c covers node c>>3, slots (c&7)*8..+7 at byte node*144 + (c&7)*16.
    {
        uint4 zr; zr.x = zr.y = zr.z = zr.w = (ZROW & 0xffffu) * 0x10001u;
#pragma unroll
        for (int r = 0; r < 2; r++) {
            int c = r * 256 + tid;               // 512 chunks total
            *(uint4*)((char*)lbkt + (c >> 3) * (BROW * 2) + (c & 7) * 16) = zr;
        }
        if (tid < BIN_NODES) lcur[tid] = 0;
    }
    __syncthreads();

    // ---- scan: own bin, unconditional clamped loads, no filter ------------
    int cnt = gCur[bin]; if (cnt > CCAP64) cnt = CCAP64;
    const unsigned int* cp = gPairs + (size_t)bin * CCAP64;
    unsigned int pw[SCAN_W];
#pragma unroll
    for (int j = 0; j < SCAN_W; j++) {
        int i = j * 256 + tid;
        pw[j] = cp[i < cnt ? i : 0];
    }
#pragma unroll
    for (int j = 0; j < SCAN_W; j++) {
        int i = j * 256 + tid;
        unsigned int pr = pw[j];
        if (i < cnt) {
            int nd = (pr >> 16) & 63;            // local node within bin
            int pos = atomicAdd(&lcur[nd], 1);
            if (pos < NODE_CAP)
                lbkt[nd * BROW + pos] = (unsigned short)(pr & 0xffffu);
        }
    }
    __syncthreads();

    // ---- gather: group g=tid>>3 (0..31), lane ln=tid&7, par=g&1 -----------
    int g = tid >> 3;
    int ln = tid & 7;
    int par = g & 1;
    int nsel = g >> 1;                           // 0..15

#pragma unroll 1
    for (int q = 0; q < 4; q++) {
        int node = q * 16 + nsel;                // 0..63
        int n = nodeBase + node;
        int valid = n < N_NODES;
        int dg = lcur[node];
        int dgc = dg < NODE_CAP ? dg : NODE_CAP;

        const float4* orow = (const float4*)(data + (size_t)(valid ? n : 0) * D + 8 * ln);
        float4 o0 = orow[0], o1 = orow[1];

        const uint2* idxp = (const uint2*)(lbkt + node * BROW + par * 4);
        uint2 iw0 = idxp[0], iw1 = idxp[2], iw2 = idxp[4], iw3 = idxp[6];

        float af[4][8];
#pragma unroll
        for (int ch = 0; ch < 4; ch++)
#pragma unroll
            for (int k = 0; k < 8; k++) af[ch][k] = 0.f;

        // ---- mask-free 16-slot batch (slots 0..31 of this parity) ---------
        // every slot holds a valid row index (ZROW pad -> adds 0.0)
        {
            unsigned int idx[16];
            unsigned int iww[8] = { iw0.x, iw0.y, iw1.x, iw1.y,
                                    iw2.x, iw2.y, iw3.x, iw3.y };
#pragma unroll
            for (int qq = 0; qq < 8; qq++) {
                idx[qq * 2]     = iww[qq] & 0xffffu;
                idx[qq * 2 + 1] = iww[qq] >> 16;
            }
            uint4 v[16];
#pragma unroll
            for (int k = 0; k < 16; k++)
                v[k] = *(const uint4*)(data16 + (size_t)idx[k] * D + 8 * ln);
#pragma unroll
            for (int k = 0; k < 16; k++) {
                int ch = k & 3;
                af[ch][0] += bflo(v[k].x); af[ch][1] += bfhi(v[k].x);
                af[ch][2] += bflo(v[k].y); af[ch][3] += bfhi(v[k].y);
                af[ch][4] += bflo(v[k].z); af[ch][5] += bfhi(v[k].z);
                af[ch][6] += bflo(v[k].w); af[ch][7] += bfhi(v[k].w);
            }
        }
        // tail: deg > 32 (~6 nodes in the whole graph); pad slots are ZROW
        int nIt = (dgc + 7) >> 3;
        for (int it = 4; it < nIt; it++) {
            uint2 iw = idxp[it * 2];
            unsigned int jdx[4] = { iw.x & 0xffffu, iw.x >> 16,
                                    iw.y & 0xffffu, iw.y >> 16 };
            uint4 vv[4];
#pragma unroll
            for (int k = 0; k < 4; k++)
                vv[k] = *(const uint4*)(data16 + (size_t)jdx[k] * D + 8 * ln);
#pragma unroll
            for (int k = 0; k < 4; k++) {
                af[k][0] += bflo(vv[k].x); af[k][1] += bfhi(vv[k].x);
                af[k][2] += bflo(vv[k].y); af[k][3] += bfhi(vv[k].y);
                af[k][4] += bflo(vv[k].z); af[k][5] += bfhi(vv[k].z);
                af[k][6] += bflo(vv[k].w); af[k][7] += bfhi(vv[k].w);
            }
        }

        float sv[8];
#pragma unroll
        for (int k = 0; k < 8; k++)
            sv[k] = (af[0][k] + af[1][k]) + (af[2][k] + af[3][k]);
#pragma unroll
        for (int k = 0; k < 8; k++) sv[k] += __shfl_xor(sv[k], 8);   // parities

        if (par == 0) {
            float inv = dg > 0 ? 1.0f / (float)dg : 0.0f;
            float msk = dg > 0 ? 1.0f : 0.0f;
            float4 h0, h1;
            h0.x = (o0.x - sv[0] * inv) * msk; h0.y = (o0.y - sv[1] * inv) * msk;
            h0.z = (o0.z - sv[2] * inv) * msk; h0.w = (o0.w - sv[3] * inv) * msk;
            h1.x = (o1.x - sv[4] * inv) * msk; h1.y = (o1.y - sv[5] * inv) * msk;
            h1.z = (o1.z - sv[6] * inv) * msk; h1.w = (o1.w - sv[7] * inv) * msk;
            // h row -> bf16 tile, cols 8ln..8ln+7 (16-byte block ln), swizzled
            union { short8t s; uint4 u; } hv;
            hv.s = pack8(h0, h1);
            st_tile(hb, node, ln * 16, hv.u);
        }
    }

    // ---- MFMA epilogue operand prefetch (latency hidden under barrier) ----
    int w = tid >> 6;
    short8t bfr[4][2];
#pragma unroll
    for (int t = 0; t < 4; t++)
#pragma unroll
        for (int s = 0; s < 2; s++) {
            const float4* wp = (const float4*)(W_lin
                + (size_t)(16 * t + (lane & 15)) * D + (lane >> 4) * 8 + s * 32);
            bfr[t][s] = pack8(wp[0], wp[1]);
        }
    float oldv[4][4];
#pragma unroll
    for (int t = 0; t < 4; t++) {
        int cl = 16 * t + (lane & 15);
#pragma unroll
        for (int j = 0; j < 4; j++) {
            int node = nodeBase + 16 * w + (lane >> 4) * 4 + j;
            oldv[t][j] = out[(size_t)(node < N_NODES ? node : 0) * D + cl];
        }
    }
    __syncthreads();

    // ---- MFMA: wave w -> rows 16w..16w+15; out = relu(h@W_lin^T + skip) ---
    f32x4 acc[4] = {{0,0,0,0},{0,0,0,0},{0,0,0,0},{0,0,0,0}};
#pragma unroll
    for (int s = 0; s < 2; s++) {
        short8t a = ld_tile(hb, 16 * w + (lane & 15), (lane >> 4) * 16 + s * 64);
#pragma unroll
        for (int t = 0; t < 4; t++)
            acc[t] = __builtin_amdgcn_mfma_f32_16x16x32_bf16(
                a, bfr[t][s], acc[t], 0, 0, 0);
    }
#pragma unroll
    for (int t = 0; t < 4; t++) {
        int cl = 16 * t + (lane & 15);
#pragma unroll
        for (int j = 0; j < 4; j++) {
            int node = nodeBase + 16 * w + (lane >> 4) * 4 + j;
            if (node < N_NODES) {
                float o = acc[t][j] + oldv[t][j];
                out[(size_t)node * D + cl] = o > 0.f ? o : 0.f;
            }
        }
    }
}

extern "C" void kernel_launch(void* const* d_in, const int* in_sizes, int n_in,
                              void* d_out, int out_size, void* d_ws, size_t ws_size,
                              hipStream_t stream) {
    const float* data  = (const float*)d_in[0];
    const float* merge = (const float*)d_in[1];
    const int*   src   = (const int*)d_in[2];
    const int*   tgt   = (const int*)d_in[3];
    // d_in[4]=W_lin, d_in[5]=b_lin (cancels in lap), d_in[6]=W_tr, d_in[7]=b_tr
    const float* W_lin = (const float*)d_in[4];
    const float* W_tr  = (const float*)d_in[6];
    const float* b_tr  = (const float*)d_in[7];
    float* out = (float*)d_out;

    // Workspace: gCur[1024 i32, flag at 1023] | gPairs[782*1280 u32] (4.0 MB)
    //            | data16[(N+1)*D bf16] (6.4 MB, row 50000 = zeros)
    char* ws = (char*)d_ws;
    size_t o = 0;
    int*            gCur   = (int*)(ws + o);            o += 1024 * 4;
    unsigned int*   gPairs = (unsigned int*)(ws + o);   o += (size_t)KBINS * CCAP64 * 4;
    unsigned short* data16 = (unsigned short*)(ws + o); o += (size_t)(N_NODES + 1) * D * 2;

    // no memset: k1 block 0 zeroes gCur in-kernel (flag handshake)

    k1_kernel<<<K1_BLOCKS, 256, 0, stream>>>(
        data, merge, src, tgt, W_tr, b_tr, data16, gCur, gPairs, out);

    k2_kernel<<<KBINS, 256, 0, stream>>>(
        data, data16, gCur, gPairs, W_lin, out);
}

// Round 12
// 128.619 us; speedup vs baseline: 3.2401x; 1.0285x over previous
//
#include <hip/hip_runtime.h>

#define N_NODES 50000
#define N_EDGES 800000
#define D 64
#define KBINS 782            // 64-node bins (tgt>>6); 782*64 = 50048 >= N
#define CCAP64 1280          // edges/bin: mean 1024, sigma 32 -> +8 sigma
#define BIN_NODES 64         // k2 nodes per block
#define NODE_CAP 64          // deg ~ Poisson(16); P(>64) ~ 1e-18
#define BROW 72              // u16 stride per node bucket in LDS (144 B)
#define KA_BLOCKS 256        // ONE KA block per CU (800000/256 = 3125 exact)
#define KA_EDGES 3125
#define KA_ITERS 13          // ceil(3125/256)
#define GEMV_BLOCKS 782      // 64 rows per block (merge@W_tr^T via MFMA)
#define CVT_BLOCKS 3125
#define K1_BLOCKS (KA_BLOCKS + GEMV_BLOCKS + CVT_BLOCKS)
#define SCAN_W 5             // ceil(CCAP64/256) scan words per thread
#define MAGIC 0x7A3F19E5u    // flag value; not byte-replicated (poison-safe)
#define ZROW 50000u          // zero row in data16 (sentinel gather target)

typedef __attribute__((ext_vector_type(8))) short short8t;   // 8 bf16 (4 VGPR)
typedef __attribute__((ext_vector_type(4))) float f32x4;     // MFMA acc

__device__ __forceinline__ unsigned int f2bf(float f) {
    unsigned int u = __builtin_bit_cast(unsigned int, f);
    return (u + 0x7fffu + ((u >> 16) & 1u)) >> 16;
}
__device__ __forceinline__ float bflo(unsigned int v) {
    return __builtin_bit_cast(float, v << 16);
}
__device__ __forceinline__ float bfhi(unsigned int v) {
    return __builtin_bit_cast(float, v & 0xffff0000u);
}
__device__ __forceinline__ short8t pack8(float4 a, float4 b) {
    union { uint4 u; short8t s; } cv;
    cv.u.x = f2bf(a.x) | (f2bf(a.y) << 16);
    cv.u.y = f2bf(a.z) | (f2bf(a.w) << 16);
    cv.u.z = f2bf(b.x) | (f2bf(b.y) << 16);
    cv.u.w = f2bf(b.z) | (f2bf(b.w) << 16);
    return cv.s;
}
// LDS bf16 tile [64 rows][64 cols] (128 B/row) with XOR swizzle (G4).
__device__ __forceinline__ short8t ld_tile(const unsigned short* t, int row, int kb) {
    int addr = (row * 128 + kb) ^ ((row & 7) << 4);
    union { uint4 u; short8t s; } cv;
    cv.u = *(const uint4*)((const char*)t + addr);
    return cv.s;
}
__device__ __forceinline__ void st_tile(unsigned short* t, int row, int kb, uint4 v) {
    int addr = (row * 128 + kb) ^ ((row & 7) << 4);
    *(uint4*)((char*)t + addr) = v;
}

// ---------------------------------------------------------------------------
// ROUND-23: SKIP the pad loads. R11 made pad slots valid (zero-row); half of
// all gather slot-loads still fetched the zero row (fixed 32 slots vs mean
// deg 16 -- ~60 MB of wasted L2 transactions device-wide). Now:
//   batch0 (slots 0..15, covers deg<=16 = 57% of nodes): unconditional.
//   batch1 (slots 16..31): group-uniform guard `16+par*4 < dgc` (~43% taken),
//     body stays mask-free (ZROW pads make skipping exact).
// Expected slots/node 32 -> ~22. Reverse of R10's flattening, keeping R11's
// mask-free bodies: R10 proved batch-1 latency was TLP-hidden, so the
// unconditional form only bought wasted loads.
// ---------------------------------------------------------------------------
__global__ __launch_bounds__(256) void k1_kernel(
        const float* __restrict__ data,
        const float* __restrict__ merge,
        const int* __restrict__ src, const int* __restrict__ tgt,
        const float* __restrict__ W_tr, const float* __restrict__ b_tr,
        unsigned short* __restrict__ data16,
        int* __restrict__ gCur, unsigned int* __restrict__ gPairs,
        float* __restrict__ outv) {
    __shared__ int hist[KBINS], rbase[KBINS], cur2[KBINS];          // 9.4 KB
    __shared__ __align__(16) unsigned short mtile[64 * 64];         // 8 KB
    int b = blockIdx.x;
    int tid = threadIdx.x;
    if (b < KA_BLOCKS) {
        int eb = b * KA_EDGES;           // n == KA_EDGES always (exact div)
        // block 0: zero gCur at the coherence point, then publish flag
        if (b == 0) {
            for (int i = tid; i < KBINS; i += 256) atomicExch(&gCur[i], 0);
            __threadfence();
            __syncthreads();
            if (tid == 0)
                atomicExch((unsigned int*)&gCur[1023], MAGIC);
        }
        for (int i = tid; i < KBINS; i += 256) { hist[i] = 0; cur2[i] = 0; }
        // ---- phase A: all loads issued unconditionally (clamped) ----------
        int tg[KA_ITERS], sr[KA_ITERS];
#pragma unroll
        for (int j = 0; j < KA_ITERS; j++) {
            int i = j * 256 + tid;
            int ic = i < KA_EDGES ? i : 0;
            tg[j] = tgt[eb + ic];
            sr[j] = src[eb + ic];
        }
        __syncthreads();                 // hist zero visible
        // ---- phase B: register-only hist pass -----------------------------
        unsigned int pe[KA_ITERS];
#pragma unroll
        for (int j = 0; j < KA_ITERS; j++) {
            int i = j * 256 + tid;
            pe[j] = ((unsigned int)tg[j] << 16) | (unsigned int)sr[j];
            if (i < KA_EDGES) atomicAdd(&hist[tg[j] >> 6], 1);
        }
        __syncthreads();
        // ---- wait for gCur zeroing (flag), then reserve runs --------------
        if (tid == 0) {
            while (atomicAdd((unsigned int*)&gCur[1023], 0u) != MAGIC) {}
        }
        __syncthreads();
        for (int i = tid; i < KBINS; i += 256)
            if (hist[i] > 0)
                rbase[i] = atomicAdd(&gCur[i], hist[i]);
        __syncthreads();
        // ---- phase C: scatter from registers ------------------------------
#pragma unroll
        for (int j = 0; j < KA_ITERS; j++) {
            int i = j * 256 + tid;
            if (i < KA_EDGES) {
                unsigned int p = pe[j];
                int c = p >> 22;                        // tgt>>6
                int pos = rbase[c] + atomicAdd(&cur2[c], 1);
                if (pos < CCAP64) gPairs[(size_t)c * CCAP64 + pos] = p;
            }
        }
    } else if (b < KA_BLOCKS + GEMV_BLOCKS) {
        // ---- skip GEMM: out[64 rows] = merge@W_tr^T + b_tr (MFMA) ---------
        int gb = b - KA_BLOCKS;
        int lane = tid & 63;
        int w = tid >> 6;
        int rowBase = gb * 64;

        // stage merge tile -> bf16 LDS (swizzled): thread (r=tid>>2, q=tid&3)
        {
            int r = tid >> 2, q = tid & 3;
            int gr = rowBase + r; if (gr >= N_NODES) gr = N_NODES - 1;
            const float4* mp = (const float4*)(merge + (size_t)gr * D + q * 16);
            float4 f0 = mp[0], f1 = mp[1], f2 = mp[2], f3 = mp[3];
            union { short8t s; uint4 u; } c0, c1;
            c0.s = pack8(f0, f1); c1.s = pack8(f2, f3);
            st_tile(mtile, r, q * 32, c0.u);
            st_tile(mtile, r, q * 32 + 16, c1.u);
        }
        // B-frags: W_tr rows 16t+(lane&15), k floats (lane>>4)*8 + s*32
        short8t bfr[4][2];
        float bias[4];
#pragma unroll
        for (int t = 0; t < 4; t++) {
            int wrow = 16 * t + (lane & 15);
            bias[t] = b_tr[wrow];
#pragma unroll
            for (int s = 0; s < 2; s++) {
                const float4* wp = (const float4*)(W_tr + (size_t)wrow * D
                                                   + (lane >> 4) * 8 + s * 32);
                bfr[t][s] = pack8(wp[0], wp[1]);
            }
        }
        __syncthreads();

        f32x4 acc[4] = {{0,0,0,0},{0,0,0,0},{0,0,0,0},{0,0,0,0}};
#pragma unroll
        for (int s = 0; s < 2; s++) {
            short8t a = ld_tile(mtile, 16 * w + (lane & 15),
                                (lane >> 4) * 16 + s * 64);
#pragma unroll
            for (int t = 0; t < 4; t++)
                acc[t] = __builtin_amdgcn_mfma_f32_16x16x32_bf16(
                    a, bfr[t][s], acc[t], 0, 0, 0);
        }
        // C/D: row=(lane>>4)*4+j (node within strip), col=lane&15
#pragma unroll
        for (int t = 0; t < 4; t++) {
            int cl = 16 * t + (lane & 15);
#pragma unroll
            for (int j = 0; j < 4; j++) {
                int node = rowBase + 16 * w + (lane >> 4) * 4 + j;
                if (node < N_NODES)
                    outv[(size_t)node * D + cl] = acc[t][j] + bias[t];
            }
        }
    } else {
        int i = (b - KA_BLOCKS - GEMV_BLOCKS) * 256 + tid;   // float4 index
        float4 d = ((const float4*)data)[i];
        uint2 v;
        v.x = f2bf(d.x) | (f2bf(d.y) << 16);
        v.y = f2bf(d.z) | (f2bf(d.w) << 16);
        ((uint2*)data16)[i] = v;
        // first CVT block also zeroes the sentinel row (index ZROW)
        if (b == KA_BLOCKS + GEMV_BLOCKS && tid < 16) {
            uint2 z; z.x = 0u; z.y = 0u;
            ((uint2*)(data16 + (size_t)ZROW * D))[tid] = z;
        }
    }
}

// ---------------------------------------------------------------------------
// K2: one block per 64-node bin. Buckets pre-filled with ZROW; gather is
// mask-free; batch1 (slots 16..31) skipped when dgc <= 16+par*4 (exact:
// those slots are all ZROW pad). MFMA epilogue: out = relu(h@W_lin^T + skip).
// ---------------------------------------------------------------------------
__global__ __launch_bounds__(256) void k2_kernel(
        const float* __restrict__ data,
        const unsigned short* __restrict__ data16,
        const int* __restrict__ gCur,
        const unsigned int* __restrict__ gPairs,
        const float* __restrict__ W_lin,
        float* __restrict__ out) {
    __shared__ __align__(16) unsigned short lbkt[BIN_NODES * BROW];  // 9 KB
    __shared__ int lcur[BIN_NODES];
    __shared__ __align__(16) unsigned short hb[BIN_NODES * D];       // 8 KB bf16

    int tid = threadIdx.x;
    int lane = tid & 63;
    int bin = blockIdx.x;
    int nodeBase = bin * BIN_NODES;

    // pre-fill bucket slots 0..63 of every node with ZROW (sentinel).
    {
        uint4 zr; zr.x = zr.y = zr.z = zr.w = (ZROW & 0xffffu) * 0x10001u;
#pragma unroll
        for (int r = 0; r < 2; r++) {
            int c = r * 256 + tid;               // 512 chunks total
            *(uint4*)((char*)lbkt + (c >> 3) * (BROW * 2) + (c & 7) * 16) = zr;
        }
        if (tid < BIN_NODES) lcur[tid] = 0;
    }
    __syncthreads();

    // ---- scan: own bin, unconditional clamped loads, no filter ------------
    int cnt = gCur[bin]; if (cnt > CCAP64) cnt = CCAP64;
    const unsigned int* cp = gPairs + (size_t)bin * CCAP64;
    unsigned int pw[SCAN_W];
#pragma unroll
    for (int j = 0; j < SCAN_W; j++) {
        int i = j * 256 + tid;
        pw[j] = cp[i < cnt ? i : 0];
    }
#pragma unroll
    for (int j = 0; j < SCAN_W; j++) {
        int i = j * 256 + tid;
        unsigned int pr = pw[j];
        if (i < cnt) {
            int nd = (pr >> 16) & 63;            // local node within bin
            int pos = atomicAdd(&lcur[nd], 1);
            if (pos < NODE_CAP)
                lbkt[nd * BROW + pos] = (unsigned short)(pr & 0xffffu);
        }
    }
    __syncthreads();

    // ---- gather: group g=tid>>3 (0..31), lane ln=tid&7, par=g&1 -----------
    int g = tid >> 3;
    int ln = tid & 7;
    int par = g & 1;
    int nsel = g >> 1;                           // 0..15

#pragma unroll 1
    for (int q = 0; q < 4; q++) {
        int node = q * 16 + nsel;                // 0..63
        int n = nodeBase + node;
        int valid = n < N_NODES;
        int dg = lcur[node];
        int dgc = dg < NODE_CAP ? dg : NODE_CAP;

        const float4* orow = (const float4*)(data + (size_t)(valid ? n : 0) * D + 8 * ln);
        float4 o0 = orow[0], o1 = orow[1];

        const uint2* idxp = (const uint2*)(lbkt + node * BROW + par * 4);
        uint2 iw0 = idxp[0], iw1 = idxp[2], iw2 = idxp[4], iw3 = idxp[6];

        float af[4][8];
#pragma unroll
        for (int ch = 0; ch < 4; ch++)
#pragma unroll
            for (int k = 0; k < 8; k++) af[ch][k] = 0.f;

        // ---- batch 0: slots it=0,1 (covers deg<=16) -- unconditional ------
        {
            unsigned int idx[8];
            unsigned int iww[4] = { iw0.x, iw0.y, iw1.x, iw1.y };
#pragma unroll
            for (int qq = 0; qq < 4; qq++) {
                idx[qq * 2]     = iww[qq] & 0xffffu;
                idx[qq * 2 + 1] = iww[qq] >> 16;
            }
            uint4 v[8];
#pragma unroll
            for (int k = 0; k < 8; k++)
                v[k] = *(const uint4*)(data16 + (size_t)idx[k] * D + 8 * ln);
#pragma unroll
            for (int k = 0; k < 8; k++) {
                int ch = k & 3;
                af[ch][0] += bflo(v[k].x); af[ch][1] += bfhi(v[k].x);
                af[ch][2] += bflo(v[k].y); af[ch][3] += bfhi(v[k].y);
                af[ch][4] += bflo(v[k].z); af[ch][5] += bfhi(v[k].z);
                af[ch][6] += bflo(v[k].w); af[ch][7] += bfhi(v[k].w);
            }
        }
        // ---- batch 1: slots it=2,3 -- group-uniform guard (43% taken) -----
        // exact skip: dgc <= 16+par*4 means every slot here is ZROW pad
        if (16 + par * 4 < dgc) {
            unsigned int idx[8];
            unsigned int iww[4] = { iw2.x, iw2.y, iw3.x, iw3.y };
#pragma unroll
            for (int qq = 0; qq < 4; qq++) {
                idx[qq * 2]     = iww[qq] & 0xffffu;
                idx[qq * 2 + 1] = iww[qq] >> 16;
            }
            uint4 v[8];
#pragma unroll
            for (int k = 0; k < 8; k++)
                v[k] = *(const uint4*)(data16 + (size_t)idx[k] * D + 8 * ln);
#pragma unroll
            for (int k = 0; k < 8; k++) {
                int ch = k & 3;
                af[ch][0] += bflo(v[k].x); af[ch][1] += bfhi(v[k].x);
                af[ch][2] += bflo(v[k].y); af[ch][3] += bfhi(v[k].y);
                af[ch][4] += bflo(v[k].z); af[ch][5] += bfhi(v[k].z);
                af[ch][6] += bflo(v[k].w); af[ch][7] += bfhi(v[k].w);
            }
        }
        // tail: deg > 32 (~6 nodes in the whole graph); pad slots are ZROW
        int nIt = (dgc + 7) >> 3;
        for (int it = 4; it < nIt; it++) {
            uint2 iw = idxp[it * 2];
            unsigned int jdx[4] = { iw.x & 0xffffu, iw.x >> 16,
                                    iw.y & 0xffffu, iw.y >> 16 };
            uint4 vv[4];
#pragma unroll
            for (int k = 0; k < 4; k++)
                vv[k] = *(const uint4*)(data16 + (size_t)jdx[k] * D + 8 * ln);
#pragma unroll
            for (int k = 0; k < 4; k++) {
                af[k][0] += bflo(vv[k].x); af[k][1] += bfhi(vv[k].x);
                af[k][2] += bflo(vv[k].y); af[k][3] += bfhi(vv[k].y);
                af[k][4] += bflo(vv[k].z); af[k][5] += bfhi(vv[k].z);
                af[k][6] += bflo(vv[k].w); af[k][7] += bfhi(vv[k].w);
            }
        }

        float sv[8];
#pragma unroll
        for (int k = 0; k < 8; k++)
            sv[k] = (af[0][k] + af[1][k]) + (af[2][k] + af[3][k]);
#pragma unroll
        for (int k = 0; k < 8; k++) sv[k] += __shfl_xor(sv[k], 8);   // parities

        if (par == 0) {
            float inv = dg > 0 ? 1.0f / (float)dg : 0.0f;
            float msk = dg > 0 ? 1.0f : 0.0f;
            float4 h0, h1;
            h0.x = (o0.x - sv[0] * inv) * msk; h0.y = (o0.y - sv[1] * inv) * msk;
            h0.z = (o0.z - sv[2] * inv) * msk; h0.w = (o0.w - sv[3] * inv) * msk;
            h1.x = (o1.x - sv[4] * inv) * msk; h1.y = (o1.y - sv[5] * inv) * msk;
            h1.z = (o1.z - sv[6] * inv) * msk; h1.w = (o1.w - sv[7] * inv) * msk;
            // h row -> bf16 tile, cols 8ln..8ln+7 (16-byte block ln), swizzled
            union { short8t s; uint4 u; } hv;
            hv.s = pack8(h0, h1);
            st_tile(hb, node, ln * 16, hv.u);
        }
    }

    // ---- MFMA epilogue operand prefetch (latency hidden under barrier) ----
    int w = tid >> 6;
    short8t bfr[4][2];
#pragma unroll
    for (int t = 0; t < 4; t++)
#pragma unroll
        for (int s = 0; s < 2; s++) {
            const float4* wp = (const float4*)(W_lin
                + (size_t)(16 * t + (lane & 15)) * D + (lane >> 4) * 8 + s * 32);
            bfr[t][s] = pack8(wp[0], wp[1]);
        }
    float oldv[4][4];
#pragma unroll
    for (int t = 0; t < 4; t++) {
        int cl = 16 * t + (lane & 15);
#pragma unroll
        for (int j = 0; j < 4; j++) {
            int node = nodeBase + 16 * w + (lane >> 4) * 4 + j;
            oldv[t][j] = out[(size_t)(node < N_NODES ? node : 0) * D + cl];
        }
    }
    __syncthreads();

    // ---- MFMA: wave w -> rows 16w..16w+15; out = relu(h@W_lin^T + skip) ---
    f32x4 acc[4] = {{0,0,0,0},{0,0,0,0},{0,0,0,0},{0,0,0,0}};
#pragma unroll
    for (int s = 0; s < 2; s++) {
        short8t a = ld_tile(hb, 16 * w + (lane & 15), (lane >> 4) * 16 + s * 64);
#pragma unroll
        for (int t = 0; t < 4; t++)
            acc[t] = __builtin_amdgcn_mfma_f32_16x16x32_bf16(
                a, bfr[t][s], acc[t], 0, 0, 0);
    }
#pragma unroll
    for (int t = 0; t < 4; t++) {
        int cl = 16 * t + (lane & 15);
#pragma unroll
        for (int j = 0; j < 4; j++) {
            int node = nodeBase + 16 * w + (lane >> 4) * 4 + j;
            if (node < N_NODES) {
                float o = acc[t][j] + oldv[t][j];
                out[(size_t)node * D + cl] = o > 0.f ? o : 0.f;
            }
        }
    }
}

extern "C" void kernel_launch(void* const* d_in, const int* in_sizes, int n_in,
                              void* d_out, int out_size, void* d_ws, size_t ws_size,
                              hipStream_t stream) {
    const float* data  = (const float*)d_in[0];
    const float* merge = (const float*)d_in[1];
    const int*   src   = (const int*)d_in[2];
    const int*   tgt   = (const int*)d_in[3];
    // d_in[4]=W_lin, d_in[5]=b_lin (cancels in lap), d_in[6]=W_tr, d_in[7]=b_tr
    const float* W_lin = (const float*)d_in[4];
    const float* W_tr  = (const float*)d_in[6];
    const float* b_tr  = (const float*)d_in[7];
    float* out = (float*)d_out;

    // Workspace: gCur[1024 i32, flag at 1023] | gPairs[782*1280 u32] (4.0 MB)
    //            | data16[(N+1)*D bf16] (6.4 MB, row 50000 = zeros)
    char* ws = (char*)d_ws;
    size_t o = 0;
    int*            gCur   = (int*)(ws + o);            o += 1024 * 4;
    unsigned int*   gPairs = (unsigned int*)(ws + o);   o += (size_t)KBINS * CCAP64 * 4;
    unsigned short* data16 = (unsigned short*)(ws + o); o += (size_t)(N_NODES + 1) * D * 2;

    // no memset: k1 block 0 zeroes gCur in-kernel (flag handshake)

    k1_kernel<<<K1_BLOCKS, 256, 0, stream>>>(
        data, merge, src, tgt, W_tr, b_tr, data16, gCur, gPairs, out);

    k2_kernel<<<KBINS, 256, 0, stream>>>(
        data, data16, gCur, gPairs, W_lin, out);
}